// Round 2
// baseline (14998.000 us; speedup 1.0000x reference)
//
#include <hip/hip_runtime.h>
#include <hip/hip_bf16.h>
#include <math.h>

// Decoder: T=64, B=48, S=64, D=1024, E=300, V=32000
#define T_LEN 64
#define BATCH 48
#define SRC   64
#define DH    1024
#define EMB   300
#define VOC   32000
#define GDIM  4096   // 4*DH
#define XDIM  1324   // DH+EMB

// ---------------------------------------------------------------------------
// Generic fp32 GEMM: C[M,N] = A[M,K] * B[N,K]^T (+bias0 +bias1) [+tanh]
// BM=BN=128, BK=8, 256 threads, 8x8 per thread.
// ---------------------------------------------------------------------------
#define BM 128
#define BN 128
#define BK 8

template<int ACT>
__global__ __launch_bounds__(256, 2) void gemm_abt(
    const float* __restrict__ A, int lda,
    const float* __restrict__ B, int ldb,
    const float* __restrict__ bias0, const float* __restrict__ bias1,
    float* __restrict__ C, int ldc, int M, int N, int K)
{
  __shared__ float As[BK][BM + 4];
  __shared__ float Bs[BK][BN + 4];
  const int tid = threadIdx.x;
  const int bm = blockIdx.x * BM;
  const int bn = blockIdx.y * BN;
  const int tr = (tid >> 4) << 3;   // 0..120
  const int tc = (tid & 15) << 3;   // 0..120

  float acc[8][8];
#pragma unroll
  for (int i = 0; i < 8; ++i)
#pragma unroll
    for (int j = 0; j < 8; ++j) acc[i][j] = 0.f;

  const int lrow = tid >> 1;          // 0..127
  const int lcol = (tid & 1) << 2;    // 0 or 4

  for (int k0 = 0; k0 < K; k0 += BK) {
    float4 av = make_float4(0.f, 0.f, 0.f, 0.f);
    {
      const int gr = bm + lrow;
      if (gr < M) {
        if (k0 + BK <= K) {
          av = *reinterpret_cast<const float4*>(A + (size_t)gr * lda + k0 + lcol);
        } else {
          float t0 = 0.f, t1 = 0.f, t2 = 0.f, t3 = 0.f;
          const int kk = k0 + lcol;
          if (kk + 0 < K) t0 = A[(size_t)gr * lda + kk + 0];
          if (kk + 1 < K) t1 = A[(size_t)gr * lda + kk + 1];
          if (kk + 2 < K) t2 = A[(size_t)gr * lda + kk + 2];
          if (kk + 3 < K) t3 = A[(size_t)gr * lda + kk + 3];
          av = make_float4(t0, t1, t2, t3);
        }
      }
    }
    float4 bv = make_float4(0.f, 0.f, 0.f, 0.f);
    {
      const int gr = bn + lrow;
      if (gr < N) {
        if (k0 + BK <= K) {
          bv = *reinterpret_cast<const float4*>(B + (size_t)gr * ldb + k0 + lcol);
        } else {
          float t0 = 0.f, t1 = 0.f, t2 = 0.f, t3 = 0.f;
          const int kk = k0 + lcol;
          if (kk + 0 < K) t0 = B[(size_t)gr * ldb + kk + 0];
          if (kk + 1 < K) t1 = B[(size_t)gr * ldb + kk + 1];
          if (kk + 2 < K) t2 = B[(size_t)gr * ldb + kk + 2];
          if (kk + 3 < K) t3 = B[(size_t)gr * ldb + kk + 3];
          bv = make_float4(t0, t1, t2, t3);
        }
      }
    }
    As[lcol + 0][lrow] = av.x; As[lcol + 1][lrow] = av.y;
    As[lcol + 2][lrow] = av.z; As[lcol + 3][lrow] = av.w;
    Bs[lcol + 0][lrow] = bv.x; Bs[lcol + 1][lrow] = bv.y;
    Bs[lcol + 2][lrow] = bv.z; Bs[lcol + 3][lrow] = bv.w;
    __syncthreads();

#pragma unroll
    for (int k = 0; k < BK; ++k) {
      float a[8], b[8];
      *reinterpret_cast<float4*>(&a[0]) = *reinterpret_cast<const float4*>(&As[k][tr]);
      *reinterpret_cast<float4*>(&a[4]) = *reinterpret_cast<const float4*>(&As[k][tr + 4]);
      *reinterpret_cast<float4*>(&b[0]) = *reinterpret_cast<const float4*>(&Bs[k][tc]);
      *reinterpret_cast<float4*>(&b[4]) = *reinterpret_cast<const float4*>(&Bs[k][tc + 4]);
#pragma unroll
      for (int i = 0; i < 8; ++i)
#pragma unroll
        for (int j = 0; j < 8; ++j) acc[i][j] = fmaf(a[i], b[j], acc[i][j]);
    }
    __syncthreads();
  }

#pragma unroll
  for (int i = 0; i < 8; ++i) {
    const int gr = bm + tr + i;
    if (gr >= M) break;
#pragma unroll
    for (int j = 0; j < 8; ++j) {
      const int gc = bn + tc + j;
      if (gc >= N) continue;
      float v = acc[i][j];
      if (bias0) v += bias0[gc];
      if (bias1) v += bias1[gc];
      if (ACT == 1) v = tanhf(v);
      C[(size_t)gr * ldc + gc] = v;
    }
  }
}

// ---------------------------------------------------------------------------
// Attention scores: sc[s,b] = sum_d enc[s,b,d] * ht[b,d].  One wave per (s,b).
// ---------------------------------------------------------------------------
__global__ __launch_bounds__(64) void scores_kernel(
    const float* __restrict__ enc, const float* __restrict__ ht,
    float* __restrict__ sc)
{
  const int sb = blockIdx.x;           // = s*BATCH + b
  const int b = sb % BATCH;
  const int lane = threadIdx.x;
  const float* e = enc + (size_t)sb * DH;
  const float* h = ht + (size_t)b * DH;
  float sum = 0.f;
  for (int k = lane * 4; k < DH; k += 64 * 4) {
    float4 ev = *reinterpret_cast<const float4*>(e + k);
    float4 hv = *reinterpret_cast<const float4*>(h + k);
    sum += ev.x * hv.x + ev.y * hv.y + ev.z * hv.z + ev.w * hv.w;
  }
#pragma unroll
  for (int off = 32; off; off >>= 1) sum += __shfl_down(sum, off);
  if (lane == 0) sc[sb] = sum;
}

// ---------------------------------------------------------------------------
// log_softmax over axis=1 (the BATCH dim) -- faithful to the reference.
// One thread per s.
// ---------------------------------------------------------------------------
__global__ __launch_bounds__(64) void logsoftmax_kernel(
    const float* __restrict__ sc, float* __restrict__ a)
{
  const int s = threadIdx.x;
  if (s >= SRC) return;
  const float* r = sc + (size_t)s * BATCH;
  float m = -INFINITY;
  for (int b = 0; b < BATCH; ++b) m = fmaxf(m, r[b]);
  float sum = 0.f;
  for (int b = 0; b < BATCH; ++b) sum += expf(r[b] - m);
  const float lse = m + logf(sum);
  float* o = a + (size_t)s * BATCH;
  for (int b = 0; b < BATCH; ++b) o[b] = r[b] - lse;
}

// ---------------------------------------------------------------------------
// cat[b, 0:1024]   = sum_s a[s,b] * enc[s,b,:]
// cat[b, 1024:2048]= hidden[b,:]
// ---------------------------------------------------------------------------
__global__ __launch_bounds__(256) void ctxsum_kernel(
    const float* __restrict__ a, const float* __restrict__ enc,
    const float* __restrict__ hidden, float* __restrict__ cat)
{
  const int b = blockIdx.x;
  const int d = blockIdx.y * 256 + threadIdx.x;
  float sum = 0.f;
  for (int s = 0; s < SRC; ++s)
    sum = fmaf(a[s * BATCH + b], enc[(size_t)(s * BATCH + b) * DH + d], sum);
  cat[(size_t)b * (2 * DH) + d] = sum;
  cat[(size_t)b * (2 * DH) + DH + d] = hidden[(size_t)b * DH + d];
}

// ---------------------------------------------------------------------------
// Embedding gather: embedded[tb, :] = emb[targ[tb], :]
// ---------------------------------------------------------------------------
__global__ __launch_bounds__(256) void gather_kernel(
    const int* __restrict__ targ, const float* __restrict__ emb,
    float* __restrict__ embedded)
{
  const int tb = blockIdx.x;
  const int tok = targ[tb];
  const float* src = emb + (size_t)tok * EMB;
  float* dst = embedded + (size_t)tb * EMB;
  for (int j = threadIdx.x; j < EMB; j += blockDim.x) dst[j] = src[j];
}

// ---------------------------------------------------------------------------
// One LSTM step. gates[b,g] = xg_t[b,g] + ctxpart[b,g] + h_in[b,:] . w_hh[g,:]
// grid: 128 blocks (8 j's each), block: 384 threads = (48 b) x (8 j).
// h_in staged through LDS in K-tiles of 256.
// ---------------------------------------------------------------------------
#define KT 256
#define HPAD 260

__global__ __launch_bounds__(384) void lstm_step_kernel(
    const float* __restrict__ xg_t,     // [BATCH, GDIM] (emb part, no bias)
    const float* __restrict__ ctxpart,  // [BATCH, GDIM] (ctx part + b_ih + b_hh)
    const float* __restrict__ w_hh,     // [GDIM, DH]
    const float* __restrict__ h_in,     // [BATCH, DH]
    float* __restrict__ h_out,          // [BATCH, DH]
    float* __restrict__ c_buf,          // [BATCH, DH] (in-place)
    float* __restrict__ hs_t,           // [BATCH, DH] slice of hs
    int first)
{
  __shared__ float hsh[48 * HPAD];
  const int tid = threadIdx.x;
  const int b = tid >> 3;          // 0..47
  const int jj = tid & 7;          // 0..7
  const int j = blockIdx.x * 8 + jj;

  float acc0 = 0.f, acc1 = 0.f, acc2 = 0.f, acc3 = 0.f;
  if (!first) {
    for (int k0 = 0; k0 < DH; k0 += KT) {
      // cooperatively stage h_in[:, k0:k0+KT] into LDS
      for (int i = tid; i < 48 * (KT / 4); i += 384) {
        const int row = i / (KT / 4);
        const int c4 = (i % (KT / 4)) * 4;
        float4 v = *reinterpret_cast<const float4*>(h_in + (size_t)row * DH + k0 + c4);
        *reinterpret_cast<float4*>(&hsh[row * HPAD + c4]) = v;
      }
      __syncthreads();
      const float* w0 = w_hh + ((size_t)(0 * DH + j)) * DH + k0;
      const float* w1 = w_hh + ((size_t)(1 * DH + j)) * DH + k0;
      const float* w2 = w_hh + ((size_t)(2 * DH + j)) * DH + k0;
      const float* w3 = w_hh + ((size_t)(3 * DH + j)) * DH + k0;
      const float* hb = &hsh[b * HPAD];
#pragma unroll 8
      for (int k = 0; k < KT; k += 4) {
        const float4 hv = *reinterpret_cast<const float4*>(hb + k);
        float4 w;
        w = *reinterpret_cast<const float4*>(w0 + k);
        acc0 += hv.x * w.x + hv.y * w.y + hv.z * w.z + hv.w * w.w;
        w = *reinterpret_cast<const float4*>(w1 + k);
        acc1 += hv.x * w.x + hv.y * w.y + hv.z * w.z + hv.w * w.w;
        w = *reinterpret_cast<const float4*>(w2 + k);
        acc2 += hv.x * w.x + hv.y * w.y + hv.z * w.z + hv.w * w.w;
        w = *reinterpret_cast<const float4*>(w3 + k);
        acc3 += hv.x * w.x + hv.y * w.y + hv.z * w.z + hv.w * w.w;
      }
      __syncthreads();
    }
  }

  const size_t gi = (size_t)b * GDIM + j;
  const float g_i = xg_t[gi + 0 * DH] + ctxpart[gi + 0 * DH] + acc0;
  const float g_f = xg_t[gi + 1 * DH] + ctxpart[gi + 1 * DH] + acc1;
  const float g_g = xg_t[gi + 2 * DH] + ctxpart[gi + 2 * DH] + acc2;
  const float g_o = xg_t[gi + 3 * DH] + ctxpart[gi + 3 * DH] + acc3;
  const float si = 1.f / (1.f + expf(-g_i));
  const float sf = 1.f / (1.f + expf(-g_f));
  const float so = 1.f / (1.f + expf(-g_o));
  const float tg = tanhf(g_g);
  const float cprev = first ? 0.f : c_buf[(size_t)b * DH + j];
  const float c = sf * cprev + si * tg;
  const float h = so * tanhf(c);
  c_buf[(size_t)b * DH + j] = c;
  h_out[(size_t)b * DH + j] = h;
  hs_t[(size_t)b * DH + j] = h;
}

// ---------------------------------------------------------------------------
extern "C" void kernel_launch(void* const* d_in, const int* in_sizes, int n_in,
                              void* d_out, int out_size, void* d_ws, size_t ws_size,
                              hipStream_t stream) {
  const int*   targ     = (const int*)d_in[0];
  const float* enc      = (const float*)d_in[1];
  const float* emb      = (const float*)d_in[2];
  const float* attin_w  = (const float*)d_in[3];
  const float* attin_b  = (const float*)d_in[4];
  const float* attout_w = (const float*)d_in[5];
  const float* attout_b = (const float*)d_in[6];
  const float* gen_w    = (const float*)d_in[7];
  const float* gen_b    = (const float*)d_in[8];
  const float* hidden   = (const float*)d_in[9];
  const float* w_ih     = (const float*)d_in[10];
  const float* w_hh     = (const float*)d_in[11];
  const float* b_ih     = (const float*)d_in[12];
  const float* b_hh     = (const float*)d_in[13];
  float* out = (float*)d_out;

  // workspace carve (total ~69 MB)
  char* wsp = (char*)d_ws;
  auto alloc = [&](size_t bytes) {
    char* p = wsp;
    wsp += (bytes + 255) & ~(size_t)255;
    return p;
  };
  float* ht       = (float*)alloc((size_t)BATCH * DH * 4);
  float* sc       = (float*)alloc((size_t)SRC * BATCH * 4);
  float* attn     = (float*)alloc((size_t)SRC * BATCH * 4);
  float* cat      = (float*)alloc((size_t)BATCH * 2 * DH * 4);
  float* ctx      = (float*)alloc((size_t)BATCH * DH * 4);
  float* ctxpart  = (float*)alloc((size_t)BATCH * GDIM * 4);
  float* embedded = (float*)alloc((size_t)T_LEN * BATCH * EMB * 4);
  float* xg       = (float*)alloc((size_t)T_LEN * BATCH * GDIM * 4);
  float* hbuf0    = (float*)alloc((size_t)BATCH * DH * 4);
  float* hbuf1    = (float*)alloc((size_t)BATCH * DH * 4);
  float* cbuf     = (float*)alloc((size_t)BATCH * DH * 4);
  float* hs       = (float*)alloc((size_t)T_LEN * BATCH * DH * 4);

  // 1. ht = hidden @ attin_w^T + attin_b            [48,1024]
  gemm_abt<0><<<dim3(1, DH / BN), 256, 0, stream>>>(
      hidden, DH, attin_w, DH, attin_b, nullptr, ht, DH, BATCH, DH, DH);

  // 2. sc[s,b] = enc[s,b,:] . ht[b,:]
  scores_kernel<<<SRC * BATCH, 64, 0, stream>>>(enc, ht, sc);

  // 3. a = log_softmax(sc, axis=1)  (over batch dim)
  logsoftmax_kernel<<<1, 64, 0, stream>>>(sc, attn);

  // 4. cat = [sum_s a*enc , hidden]                 [48,2048]
  ctxsum_kernel<<<dim3(BATCH, DH / 256), 256, 0, stream>>>(attn, enc, hidden, cat);

  // 5. context = tanh(cat @ attout_w^T + attout_b)  [48,1024]
  gemm_abt<1><<<dim3(1, DH / BN), 256, 0, stream>>>(
      cat, 2 * DH, attout_w, 2 * DH, attout_b, nullptr, ctx, DH, BATCH, DH, 2 * DH);

  // 6. ctxpart = context @ w_ih[:, :1024]^T + b_ih + b_hh   [48,4096]
  gemm_abt<0><<<dim3(1, GDIM / BN), 256, 0, stream>>>(
      ctx, DH, w_ih, XDIM, b_ih, b_hh, ctxpart, GDIM, BATCH, GDIM, DH);

  // 7. embedded = emb[targ]                          [3072,300]
  gather_kernel<<<T_LEN * BATCH, 256, 0, stream>>>(targ, emb, embedded);

  // 8. xg = embedded @ w_ih[:, 1024:]^T              [3072,4096]
  gemm_abt<0><<<dim3(T_LEN * BATCH / BM, GDIM / BN), 256, 0, stream>>>(
      embedded, EMB, w_ih + DH, XDIM, nullptr, nullptr, xg, GDIM,
      T_LEN * BATCH, GDIM, EMB);

  // 9. LSTM over 64 steps
  for (int t = 0; t < T_LEN; ++t) {
    const float* hin = (t & 1) ? hbuf1 : hbuf0;
    float* hout = (t & 1) ? hbuf0 : hbuf1;
    lstm_step_kernel<<<DH / 8, 384, 0, stream>>>(
        xg + (size_t)t * BATCH * GDIM, ctxpart, w_hh, hin, hout, cbuf,
        hs + (size_t)t * BATCH * DH, t == 0 ? 1 : 0);
  }

  // 10. out = hs @ gen_w^T + gen_b                   [3072,32000]
  gemm_abt<0><<<dim3(T_LEN * BATCH / BM, VOC / BN), 256, 0, stream>>>(
      hs, DH, gen_w, DH, gen_b, nullptr, out, VOC,
      T_LEN * BATCH, VOC, DH);
}

// Round 4
// 4313.797 us; speedup vs baseline: 3.4768x; 3.4768x over previous
//
#include <hip/hip_runtime.h>
#include <hip/hip_bf16.h>
#include <math.h>

// Decoder: T=64, B=48, S=64, D=1024, E=300, V=32000
#define T_LEN 64
#define BATCH 48
#define SRC   64
#define DH    1024
#define EMB   300
#define VOC   32000
#define GDIM  4096   // 4*DH
#define XDIM  1324   // DH+EMB

typedef unsigned short u16;
typedef __attribute__((ext_vector_type(8))) short bf16x8;
typedef __attribute__((ext_vector_type(4))) float f32x4;

__device__ inline u16 f2bf(float f) {
  unsigned u = __float_as_uint(f);
  unsigned r = u + 0x7FFFu + ((u >> 16) & 1u);   // RNE
  return (u16)(r >> 16);
}
__device__ inline unsigned pack2bf(float lo, float hi) {
  return (unsigned)f2bf(lo) | ((unsigned)f2bf(hi) << 16);
}

// ---------------------------------------------------------------------------
// Generic fp32 GEMM: C[M,N] = A[M,K] * B[N,K]^T (+bias0 +bias1) [+tanh]
// (used for the small attention GEMMs and the xg GEMM)
// ---------------------------------------------------------------------------
#define BM 128
#define BN 128
#define BK 8

template<int ACT>
__global__ __launch_bounds__(256, 2) void gemm_abt(
    const float* __restrict__ A, int lda,
    const float* __restrict__ B, int ldb,
    const float* __restrict__ bias0, const float* __restrict__ bias1,
    float* __restrict__ C, int ldc, int M, int N, int K)
{
  __shared__ float As[BK][BM + 4];
  __shared__ float Bs[BK][BN + 4];
  const int tid = threadIdx.x;
  const int bm = blockIdx.x * BM;
  const int bn = blockIdx.y * BN;
  const int tr = (tid >> 4) << 3;
  const int tc = (tid & 15) << 3;

  float acc[8][8];
#pragma unroll
  for (int i = 0; i < 8; ++i)
#pragma unroll
    for (int j = 0; j < 8; ++j) acc[i][j] = 0.f;

  const int lrow = tid >> 1;
  const int lcol = (tid & 1) << 2;

  for (int k0 = 0; k0 < K; k0 += BK) {
    float4 av = make_float4(0.f, 0.f, 0.f, 0.f);
    {
      const int gr = bm + lrow;
      if (gr < M) {
        if (k0 + BK <= K) {
          av = *reinterpret_cast<const float4*>(A + (size_t)gr * lda + k0 + lcol);
        } else {
          float t0 = 0.f, t1 = 0.f, t2 = 0.f, t3 = 0.f;
          const int kk = k0 + lcol;
          if (kk + 0 < K) t0 = A[(size_t)gr * lda + kk + 0];
          if (kk + 1 < K) t1 = A[(size_t)gr * lda + kk + 1];
          if (kk + 2 < K) t2 = A[(size_t)gr * lda + kk + 2];
          if (kk + 3 < K) t3 = A[(size_t)gr * lda + kk + 3];
          av = make_float4(t0, t1, t2, t3);
        }
      }
    }
    float4 bv = make_float4(0.f, 0.f, 0.f, 0.f);
    {
      const int gr = bn + lrow;
      if (gr < N) {
        if (k0 + BK <= K) {
          bv = *reinterpret_cast<const float4*>(B + (size_t)gr * ldb + k0 + lcol);
        } else {
          float t0 = 0.f, t1 = 0.f, t2 = 0.f, t3 = 0.f;
          const int kk = k0 + lcol;
          if (kk + 0 < K) t0 = B[(size_t)gr * ldb + kk + 0];
          if (kk + 1 < K) t1 = B[(size_t)gr * ldb + kk + 1];
          if (kk + 2 < K) t2 = B[(size_t)gr * ldb + kk + 2];
          if (kk + 3 < K) t3 = B[(size_t)gr * ldb + kk + 3];
          bv = make_float4(t0, t1, t2, t3);
        }
      }
    }
    As[lcol + 0][lrow] = av.x; As[lcol + 1][lrow] = av.y;
    As[lcol + 2][lrow] = av.z; As[lcol + 3][lrow] = av.w;
    Bs[lcol + 0][lrow] = bv.x; Bs[lcol + 1][lrow] = bv.y;
    Bs[lcol + 2][lrow] = bv.z; Bs[lcol + 3][lrow] = bv.w;
    __syncthreads();

#pragma unroll
    for (int k = 0; k < BK; ++k) {
      float a[8], b[8];
      *reinterpret_cast<float4*>(&a[0]) = *reinterpret_cast<const float4*>(&As[k][tr]);
      *reinterpret_cast<float4*>(&a[4]) = *reinterpret_cast<const float4*>(&As[k][tr + 4]);
      *reinterpret_cast<float4*>(&b[0]) = *reinterpret_cast<const float4*>(&Bs[k][tc]);
      *reinterpret_cast<float4*>(&b[4]) = *reinterpret_cast<const float4*>(&Bs[k][tc + 4]);
#pragma unroll
      for (int i = 0; i < 8; ++i)
#pragma unroll
        for (int j = 0; j < 8; ++j) acc[i][j] = fmaf(a[i], b[j], acc[i][j]);
    }
    __syncthreads();
  }

#pragma unroll
  for (int i = 0; i < 8; ++i) {
    const int gr = bm + tr + i;
    if (gr >= M) break;
#pragma unroll
    for (int j = 0; j < 8; ++j) {
      const int gc = bn + tc + j;
      if (gc >= N) continue;
      float v = acc[i][j];
      if (bias0) v += bias0[gc];
      if (bias1) v += bias1[gc];
      if (ACT == 1) v = tanhf(v);
      C[(size_t)gr * ldc + gc] = v;
    }
  }
}

// ---------------------------------------------------------------------------
// bf16 MFMA GEMM: C[M,N] = A[M,K](bf16) * B[N,K](fp32, cvt on stage)^T + bias
// 128x128 tile, BK=32, 256 thr = 4 waves, each wave 64x64 via 4x4 frags of
// mfma_f32_16x16x32_bf16.  M,N,K must be multiples of 128/128/32.
// ---------------------------------------------------------------------------
__global__ __launch_bounds__(256) void gemm_bf16_mfma(
    const u16* __restrict__ A,          // [M,K] bf16
    const float* __restrict__ B,        // [N,K] fp32
    const float* __restrict__ bias,     // [N]
    float* __restrict__ C, int M, int N, int K)
{
  __shared__ u16 As[128 * 32];
  __shared__ u16 Bs[128 * 32];
  const int tid = threadIdx.x;
  const int lane = tid & 63;
  const int wv = tid >> 6;
  const int wr = wv >> 1, wc = wv & 1;
  const int bm = blockIdx.x * 128;
  const int bn = blockIdx.y * 128;

  const int srow = tid >> 1;            // 0..127
  const int scol = (tid & 1) << 4;      // 0 or 16 (elements)

  const u16*  Ap = A + (size_t)(bm + srow) * K + scol;
  const float* Bp = B + (size_t)(bn + srow) * K + scol;

  f32x4 acc[4][4];
#pragma unroll
  for (int i = 0; i < 4; ++i)
#pragma unroll
    for (int j = 0; j < 4; ++j) acc[i][j] = (f32x4){0.f, 0.f, 0.f, 0.f};

  // prefetch tile 0
  f32x4 a0 = *(const f32x4*)(Ap);
  f32x4 a1 = *(const f32x4*)(Ap + 8);
  float4 q0 = *(const float4*)(Bp);
  float4 q1 = *(const float4*)(Bp + 4);
  float4 q2 = *(const float4*)(Bp + 8);
  float4 q3 = *(const float4*)(Bp + 12);

  for (int k0 = 0; k0 < K; k0 += 32) {
    *(f32x4*)(&As[srow * 32 + scol]) = a0;
    *(f32x4*)(&As[srow * 32 + scol + 8]) = a1;
    uint4 w0, w1;
    w0.x = pack2bf(q0.x, q0.y); w0.y = pack2bf(q0.z, q0.w);
    w0.z = pack2bf(q1.x, q1.y); w0.w = pack2bf(q1.z, q1.w);
    w1.x = pack2bf(q2.x, q2.y); w1.y = pack2bf(q2.z, q2.w);
    w1.z = pack2bf(q3.x, q3.y); w1.w = pack2bf(q3.z, q3.w);
    *(uint4*)(&Bs[srow * 32 + scol]) = w0;
    *(uint4*)(&Bs[srow * 32 + scol + 8]) = w1;
    __syncthreads();

    if (k0 + 32 < K) {   // prefetch next tile (overlaps MFMA below)
      a0 = *(const f32x4*)(Ap + k0 + 32);
      a1 = *(const f32x4*)(Ap + k0 + 40);
      q0 = *(const float4*)(Bp + k0 + 32);
      q1 = *(const float4*)(Bp + k0 + 36);
      q2 = *(const float4*)(Bp + k0 + 40);
      q3 = *(const float4*)(Bp + k0 + 44);
    }

    bf16x8 af[4], bfr[4];
#pragma unroll
    for (int mi = 0; mi < 4; ++mi)
      af[mi] = *(const bf16x8*)(&As[(wr * 64 + mi * 16 + (lane & 15)) * 32 + (lane >> 4) * 8]);
#pragma unroll
    for (int ni = 0; ni < 4; ++ni)
      bfr[ni] = *(const bf16x8*)(&Bs[(wc * 64 + ni * 16 + (lane & 15)) * 32 + (lane >> 4) * 8]);
#pragma unroll
    for (int mi = 0; mi < 4; ++mi)
#pragma unroll
      for (int ni = 0; ni < 4; ++ni)
        acc[mi][ni] = __builtin_amdgcn_mfma_f32_16x16x32_bf16(af[mi], bfr[ni], acc[mi][ni], 0, 0, 0);
    __syncthreads();
  }

  // epilogue: C/D layout col=lane&15, row=(lane>>4)*4+reg   [m89 verified]
  const int r0 = bm + wr * 64 + ((lane >> 4) << 2);
  const int c0 = bn + wc * 64 + (lane & 15);
#pragma unroll
  for (int mi = 0; mi < 4; ++mi)
#pragma unroll
    for (int ni = 0; ni < 4; ++ni) {
      const int col = c0 + ni * 16;
      const float bv = bias[col];
#pragma unroll
      for (int r = 0; r < 4; ++r)
        C[(size_t)(r0 + mi * 16 + r) * N + col] = acc[mi][ni][r] + bv;
    }
}

// ---------------------------------------------------------------------------
// Attention scores: sc[s,b] = sum_d enc[s,b,d] * ht[b,d].
// ---------------------------------------------------------------------------
__global__ __launch_bounds__(64) void scores_kernel(
    const float* __restrict__ enc, const float* __restrict__ ht,
    float* __restrict__ sc)
{
  const int sb = blockIdx.x;
  const int b = sb % BATCH;
  const int lane = threadIdx.x;
  const float* e = enc + (size_t)sb * DH;
  const float* h = ht + (size_t)b * DH;
  float sum = 0.f;
  for (int k = lane * 4; k < DH; k += 64 * 4) {
    float4 ev = *reinterpret_cast<const float4*>(e + k);
    float4 hv = *reinterpret_cast<const float4*>(h + k);
    sum += ev.x * hv.x + ev.y * hv.y + ev.z * hv.z + ev.w * hv.w;
  }
#pragma unroll
  for (int off = 32; off; off >>= 1) sum += __shfl_down(sum, off);
  if (lane == 0) sc[sb] = sum;
}

// log_softmax over axis=1 (the BATCH dim) -- faithful to the reference.
__global__ __launch_bounds__(64) void logsoftmax_kernel(
    const float* __restrict__ sc, float* __restrict__ a)
{
  const int s = threadIdx.x;
  if (s >= SRC) return;
  const float* r = sc + (size_t)s * BATCH;
  float m = -INFINITY;
  for (int b = 0; b < BATCH; ++b) m = fmaxf(m, r[b]);
  float sum = 0.f;
  for (int b = 0; b < BATCH; ++b) sum += expf(r[b] - m);
  const float lse = m + logf(sum);
  float* o = a + (size_t)s * BATCH;
  for (int b = 0; b < BATCH; ++b) o[b] = r[b] - lse;
}

__global__ __launch_bounds__(256) void ctxsum_kernel(
    const float* __restrict__ a, const float* __restrict__ enc,
    const float* __restrict__ hidden, float* __restrict__ cat)
{
  const int b = blockIdx.x;
  const int d = blockIdx.y * 256 + threadIdx.x;
  float sum = 0.f;
  for (int s = 0; s < SRC; ++s)
    sum = fmaf(a[s * BATCH + b], enc[(size_t)(s * BATCH + b) * DH + d], sum);
  cat[(size_t)b * (2 * DH) + d] = sum;
  cat[(size_t)b * (2 * DH) + DH + d] = hidden[(size_t)b * DH + d];
}

__global__ __launch_bounds__(256) void gather_kernel(
    const int* __restrict__ targ, const float* __restrict__ emb,
    float* __restrict__ embedded)
{
  const int tb = blockIdx.x;
  const int tok = targ[tb];
  const float* src = emb + (size_t)tok * EMB;
  float* dst = embedded + (size_t)tb * EMB;
  for (int j = threadIdx.x; j < EMB; j += blockDim.x) dst[j] = src[j];
}

// ---------------------------------------------------------------------------
// LSTM recurrent GEMV: gates[b, gj] = h_in[b,:] . w_hh[gj,:]
// block = 256 thr = 4 waves; wave w -> b = bx*4+w; within a wave:
//   lane>>4 = one of 4 gj (shared across waves), lane&15 = k-slice.
// grid = (12 b-tiles FAST, 1024 gj-tiles) so 12 consecutive blocks share the
// same 4 w_hh rows (L2-hot).  16-lane shuffle reduce.
// ---------------------------------------------------------------------------
__global__ __launch_bounds__(256) void lstm_gates_kernel(
    const float* __restrict__ h_in, const float* __restrict__ w_hh,
    float* __restrict__ gates)
{
  const int lane = threadIdx.x & 63;
  const int wv = threadIdx.x >> 6;
  const int b = blockIdx.x * 4 + wv;
  const int gj = blockIdx.y * 4 + (lane >> 4);
  const int kl = (lane & 15) * 4;
  const float* wrow = w_hh + (size_t)gj * DH + kl;
  const float* hrow = h_in + (size_t)b * DH + kl;
  float acc = 0.f;
#pragma unroll
  for (int kk = 0; kk < 16; ++kk) {
    float4 w4 = *(const float4*)(wrow + kk * 64);
    float4 h4 = *(const float4*)(hrow + kk * 64);
    acc += w4.x * h4.x + w4.y * h4.y + w4.z * h4.z + w4.w * h4.w;
  }
  acc += __shfl_xor(acc, 1);
  acc += __shfl_xor(acc, 2);
  acc += __shfl_xor(acc, 4);
  acc += __shfl_xor(acc, 8);
  if ((lane & 15) == 0) gates[(size_t)b * GDIM + gj] = acc;
}

// ---------------------------------------------------------------------------
// LSTM pointwise: fold xg+ctxpart(+recurrent gates), activations, c/h update.
// Writes h (fp32, for recurrence) and hs slice (bf16, for the output GEMM).
// ---------------------------------------------------------------------------
__global__ __launch_bounds__(256) void lstm_act_kernel(
    const float* __restrict__ gates, const float* __restrict__ xg_t,
    const float* __restrict__ ctxpart, float* __restrict__ h_out,
    float* __restrict__ c_buf, u16* __restrict__ hs_t, int first)
{
  const int idx = blockIdx.x * 256 + threadIdx.x;   // b*1024 + j
  const int b = idx >> 10, j = idx & 1023;
  const size_t g0 = (size_t)b * GDIM + j;
  float gi = xg_t[g0 + 0 * DH] + ctxpart[g0 + 0 * DH];
  float gf = xg_t[g0 + 1 * DH] + ctxpart[g0 + 1 * DH];
  float gg = xg_t[g0 + 2 * DH] + ctxpart[g0 + 2 * DH];
  float go = xg_t[g0 + 3 * DH] + ctxpart[g0 + 3 * DH];
  if (!first) {
    gi += gates[g0 + 0 * DH];
    gf += gates[g0 + 1 * DH];
    gg += gates[g0 + 2 * DH];
    go += gates[g0 + 3 * DH];
  }
  const float si = 1.f / (1.f + expf(-gi));
  const float sf = 1.f / (1.f + expf(-gf));
  const float so = 1.f / (1.f + expf(-go));
  const float tg = tanhf(gg);
  const float cp = first ? 0.f : c_buf[idx];
  const float c = sf * cp + si * tg;
  const float h = so * tanhf(c);
  c_buf[idx] = c;
  h_out[idx] = h;
  hs_t[idx] = f2bf(h);
}

// ---------------------------------------------------------------------------
extern "C" void kernel_launch(void* const* d_in, const int* in_sizes, int n_in,
                              void* d_out, int out_size, void* d_ws, size_t ws_size,
                              hipStream_t stream) {
  const int*   targ     = (const int*)d_in[0];
  const float* enc      = (const float*)d_in[1];
  const float* emb      = (const float*)d_in[2];
  const float* attin_w  = (const float*)d_in[3];
  const float* attin_b  = (const float*)d_in[4];
  const float* attout_w = (const float*)d_in[5];
  const float* attout_b = (const float*)d_in[6];
  const float* gen_w    = (const float*)d_in[7];
  const float* gen_b    = (const float*)d_in[8];
  const float* hidden   = (const float*)d_in[9];
  const float* w_ih     = (const float*)d_in[10];
  const float* w_hh     = (const float*)d_in[11];
  const float* b_ih     = (const float*)d_in[12];
  const float* b_hh     = (const float*)d_in[13];
  float* out = (float*)d_out;

  // workspace carve (~64 MB)
  char* wsp = (char*)d_ws;
  auto alloc = [&](size_t bytes) {
    char* p = wsp;
    wsp += (bytes + 255) & ~(size_t)255;
    return p;
  };
  float* ht       = (float*)alloc((size_t)BATCH * DH * 4);
  float* sc       = (float*)alloc((size_t)SRC * BATCH * 4);
  float* attn     = (float*)alloc((size_t)SRC * BATCH * 4);
  float* cat      = (float*)alloc((size_t)BATCH * 2 * DH * 4);
  float* ctx      = (float*)alloc((size_t)BATCH * DH * 4);
  float* ctxpart  = (float*)alloc((size_t)BATCH * GDIM * 4);
  float* embedded = (float*)alloc((size_t)T_LEN * BATCH * EMB * 4);
  float* xg       = (float*)alloc((size_t)T_LEN * BATCH * GDIM * 4);
  float* hbuf0    = (float*)alloc((size_t)BATCH * DH * 4);
  float* hbuf1    = (float*)alloc((size_t)BATCH * DH * 4);
  float* cbuf     = (float*)alloc((size_t)BATCH * DH * 4);
  float* gates    = (float*)alloc((size_t)BATCH * GDIM * 4);
  u16*   hs_bf16  = (u16*)alloc((size_t)T_LEN * BATCH * DH * 2);

  // 1. ht = hidden @ attin_w^T + attin_b            [48,1024]
  gemm_abt<0><<<dim3(1, DH / BN), 256, 0, stream>>>(
      hidden, DH, attin_w, DH, attin_b, nullptr, ht, DH, BATCH, DH, DH);

  // 2. sc[s,b] = enc[s,b,:] . ht[b,:]
  scores_kernel<<<SRC * BATCH, 64, 0, stream>>>(enc, ht, sc);

  // 3. a = log_softmax(sc, axis=1)  (over batch dim)
  logsoftmax_kernel<<<1, 64, 0, stream>>>(sc, attn);

  // 4. cat = [sum_s a*enc , hidden]                 [48,2048]
  ctxsum_kernel<<<dim3(BATCH, DH / 256), 256, 0, stream>>>(attn, enc, hidden, cat);

  // 5. context = tanh(cat @ attout_w^T + attout_b)  [48,1024]
  gemm_abt<1><<<dim3(1, DH / BN), 256, 0, stream>>>(
      cat, 2 * DH, attout_w, 2 * DH, attout_b, nullptr, ctx, DH, BATCH, DH, 2 * DH);

  // 6. ctxpart = context @ w_ih[:, :1024]^T + b_ih + b_hh   [48,4096]
  gemm_abt<0><<<dim3(1, GDIM / BN), 256, 0, stream>>>(
      ctx, DH, w_ih, XDIM, b_ih, b_hh, ctxpart, GDIM, BATCH, GDIM, DH);

  // 7. embedded = emb[targ]                          [3072,300]
  gather_kernel<<<T_LEN * BATCH, 256, 0, stream>>>(targ, emb, embedded);

  // 8. xg = embedded @ w_ih[:, 1024:]^T              [3072,4096]
  gemm_abt<0><<<dim3(T_LEN * BATCH / BM, GDIM / BN), 256, 0, stream>>>(
      embedded, EMB, w_ih + DH, XDIM, nullptr, nullptr, xg, GDIM,
      T_LEN * BATCH, GDIM, EMB);

  // 9. LSTM over 64 steps: parallel gates GEMV + pointwise
  for (int t = 0; t < T_LEN; ++t) {
    const float* hin = (t & 1) ? hbuf1 : hbuf0;
    float* hout = (t & 1) ? hbuf0 : hbuf1;
    if (t > 0)
      lstm_gates_kernel<<<dim3(12, 1024), 256, 0, stream>>>(hin, w_hh, gates);
    lstm_act_kernel<<<BATCH * DH / 256, 256, 0, stream>>>(
        gates, xg + (size_t)t * BATCH * GDIM, ctxpart, hout, cbuf,
        hs_bf16 + (size_t)t * BATCH * DH, t == 0 ? 1 : 0);
  }

  // 10. out = hs(bf16) @ gen_w^T + gen_b   [3072,32000]  (MFMA)
  gemm_bf16_mfma<<<dim3(T_LEN * BATCH / 128, VOC / 128), 256, 0, stream>>>(
      hs_bf16, gen_w, gen_b, out, T_LEN * BATCH, VOC, DH);
}

// Round 6
// 2296.518 us; speedup vs baseline: 6.5308x; 1.8784x over previous
//
#include <hip/hip_runtime.h>
#include <hip/hip_bf16.h>
#include <math.h>

// Decoder: T=64, B=48, S=64, D=1024, E=300, V=32000
#define T_LEN 64
#define BATCH 48
#define SRC   64
#define DH    1024
#define EMB   300
#define VOC   32000
#define GDIM  4096   // 4*DH
#define XDIM  1324   // DH+EMB

typedef unsigned short u16;
typedef __attribute__((ext_vector_type(8))) short bf16x8;
typedef __attribute__((ext_vector_type(4))) float f32x4;

__device__ inline u16 f2bf(float f) {
  unsigned u = __float_as_uint(f);
  unsigned r = u + 0x7FFFu + ((u >> 16) & 1u);   // RNE
  return (u16)(r >> 16);
}
__device__ inline unsigned pack2bf(float lo, float hi) {
  return (unsigned)f2bf(lo) | ((unsigned)f2bf(hi) << 16);
}

// ---------------------------------------------------------------------------
// Generic fp32 GEMM: C[M,N] = A[M,K] * B[N,K]^T (+bias0 +bias1) [+tanh]
// (used for the small attention GEMMs and the xg GEMM)
// ---------------------------------------------------------------------------
#define BM 128
#define BN 128
#define BK 8

template<int ACT>
__global__ __launch_bounds__(256, 2) void gemm_abt(
    const float* __restrict__ A, int lda,
    const float* __restrict__ B, int ldb,
    const float* __restrict__ bias0, const float* __restrict__ bias1,
    float* __restrict__ C, int ldc, int M, int N, int K)
{
  __shared__ float As[BK][BM + 4];
  __shared__ float Bs[BK][BN + 4];
  const int tid = threadIdx.x;
  const int bm = blockIdx.x * BM;
  const int bn = blockIdx.y * BN;
  const int tr = (tid >> 4) << 3;
  const int tc = (tid & 15) << 3;

  float acc[8][8];
#pragma unroll
  for (int i = 0; i < 8; ++i)
#pragma unroll
    for (int j = 0; j < 8; ++j) acc[i][j] = 0.f;

  const int lrow = tid >> 1;
  const int lcol = (tid & 1) << 2;

  for (int k0 = 0; k0 < K; k0 += BK) {
    float4 av = make_float4(0.f, 0.f, 0.f, 0.f);
    {
      const int gr = bm + lrow;
      if (gr < M) {
        if (k0 + BK <= K) {
          av = *reinterpret_cast<const float4*>(A + (size_t)gr * lda + k0 + lcol);
        } else {
          float t0 = 0.f, t1 = 0.f, t2 = 0.f, t3 = 0.f;
          const int kk = k0 + lcol;
          if (kk + 0 < K) t0 = A[(size_t)gr * lda + kk + 0];
          if (kk + 1 < K) t1 = A[(size_t)gr * lda + kk + 1];
          if (kk + 2 < K) t2 = A[(size_t)gr * lda + kk + 2];
          if (kk + 3 < K) t3 = A[(size_t)gr * lda + kk + 3];
          av = make_float4(t0, t1, t2, t3);
        }
      }
    }
    float4 bv = make_float4(0.f, 0.f, 0.f, 0.f);
    {
      const int gr = bn + lrow;
      if (gr < N) {
        if (k0 + BK <= K) {
          bv = *reinterpret_cast<const float4*>(B + (size_t)gr * ldb + k0 + lcol);
        } else {
          float t0 = 0.f, t1 = 0.f, t2 = 0.f, t3 = 0.f;
          const int kk = k0 + lcol;
          if (kk + 0 < K) t0 = B[(size_t)gr * ldb + kk + 0];
          if (kk + 1 < K) t1 = B[(size_t)gr * ldb + kk + 1];
          if (kk + 2 < K) t2 = B[(size_t)gr * ldb + kk + 2];
          if (kk + 3 < K) t3 = B[(size_t)gr * ldb + kk + 3];
          bv = make_float4(t0, t1, t2, t3);
        }
      }
    }
    As[lcol + 0][lrow] = av.x; As[lcol + 1][lrow] = av.y;
    As[lcol + 2][lrow] = av.z; As[lcol + 3][lrow] = av.w;
    Bs[lcol + 0][lrow] = bv.x; Bs[lcol + 1][lrow] = bv.y;
    Bs[lcol + 2][lrow] = bv.z; Bs[lcol + 3][lrow] = bv.w;
    __syncthreads();

#pragma unroll
    for (int k = 0; k < BK; ++k) {
      float a[8], b[8];
      *reinterpret_cast<float4*>(&a[0]) = *reinterpret_cast<const float4*>(&As[k][tr]);
      *reinterpret_cast<float4*>(&a[4]) = *reinterpret_cast<const float4*>(&As[k][tr + 4]);
      *reinterpret_cast<float4*>(&b[0]) = *reinterpret_cast<const float4*>(&Bs[k][tc]);
      *reinterpret_cast<float4*>(&b[4]) = *reinterpret_cast<const float4*>(&Bs[k][tc + 4]);
#pragma unroll
      for (int i = 0; i < 8; ++i)
#pragma unroll
        for (int j = 0; j < 8; ++j) acc[i][j] = fmaf(a[i], b[j], acc[i][j]);
    }
    __syncthreads();
  }

#pragma unroll
  for (int i = 0; i < 8; ++i) {
    const int gr = bm + tr + i;
    if (gr >= M) break;
#pragma unroll
    for (int j = 0; j < 8; ++j) {
      const int gc = bn + tc + j;
      if (gc >= N) continue;
      float v = acc[i][j];
      if (bias0) v += bias0[gc];
      if (bias1) v += bias1[gc];
      if (ACT == 1) v = tanhf(v);
      C[(size_t)gr * ldc + gc] = v;
    }
  }
}

// ---------------------------------------------------------------------------
// bf16 MFMA GEMM: C[M,N] = A[M,K](bf16) * B[N,K](fp32, cvt on stage)^T + bias
// 128x128 tile, BK=32, 4 waves, each wave 64x64 via 4x4 frags of
// mfma_f32_16x16x32_bf16.  XCD-chunked 1-D grid; XOR-swizzled LDS.
// ---------------------------------------------------------------------------
__device__ inline int lds_idx(int row, int chunk) {
  // 64B rows, 16B chunks; chunk' = chunk ^ ((row>>1)&3)  -> 2-way max conflict
  return row * 32 + ((chunk ^ ((row >> 1) & 3)) << 3);   // u16 units
}

__global__ __launch_bounds__(256) void gemm_bf16_mfma(
    const u16* __restrict__ A,          // [M,K] bf16
    const float* __restrict__ B,        // [N,K] fp32
    const float* __restrict__ bias,     // [N]
    float* __restrict__ C, int M, int N, int K)
{
  __shared__ u16 As[128 * 32];
  __shared__ u16 Bs[128 * 32];
  const int tid = threadIdx.x;
  const int lane = tid & 63;
  const int wv = tid >> 6;
  const int wr = wv >> 1, wc = wv & 1;

  // XCD-aware bijective remap (grid must be divisible by 8)
  const int nmt = M >> 7;                       // m-tiles (fast dim)
  const int chunk_sz = (int)gridDim.x >> 3;     // per-XCD chunk
  const int bid = (int)blockIdx.x;
  const int wg = (bid & 7) * chunk_sz + (bid >> 3);
  const int bm = (wg % nmt) * 128;
  const int bn = (wg / nmt) * 128;

  const int srow = tid >> 1;            // 0..127
  const int c0 = (tid & 1) << 1;        // chunk 0 or 2

  const u16*  Ap = A + (size_t)(bm + srow) * K + (c0 << 3);
  const float* Bp = B + (size_t)(bn + srow) * K + (c0 << 3);

  f32x4 acc[4][4];
#pragma unroll
  for (int i = 0; i < 4; ++i)
#pragma unroll
    for (int j = 0; j < 4; ++j) acc[i][j] = (f32x4){0.f, 0.f, 0.f, 0.f};

  // prefetch tile 0
  f32x4 a0 = *(const f32x4*)(Ap);
  f32x4 a1 = *(const f32x4*)(Ap + 8);
  float4 q0 = *(const float4*)(Bp);
  float4 q1 = *(const float4*)(Bp + 4);
  float4 q2 = *(const float4*)(Bp + 8);
  float4 q3 = *(const float4*)(Bp + 12);

  for (int k0 = 0; k0 < K; k0 += 32) {
    *(f32x4*)(&As[lds_idx(srow, c0)]) = a0;
    *(f32x4*)(&As[lds_idx(srow, c0 + 1)]) = a1;
    uint4 w0, w1;
    w0.x = pack2bf(q0.x, q0.y); w0.y = pack2bf(q0.z, q0.w);
    w0.z = pack2bf(q1.x, q1.y); w0.w = pack2bf(q1.z, q1.w);
    w1.x = pack2bf(q2.x, q2.y); w1.y = pack2bf(q2.z, q2.w);
    w1.z = pack2bf(q3.x, q3.y); w1.w = pack2bf(q3.z, q3.w);
    *(uint4*)(&Bs[lds_idx(srow, c0)]) = w0;
    *(uint4*)(&Bs[lds_idx(srow, c0 + 1)]) = w1;
    __syncthreads();

    if (k0 + 32 < K) {   // prefetch next tile (overlaps MFMA below)
      a0 = *(const f32x4*)(Ap + k0 + 32);
      a1 = *(const f32x4*)(Ap + k0 + 40);
      q0 = *(const float4*)(Bp + k0 + 32);
      q1 = *(const float4*)(Bp + k0 + 36);
      q2 = *(const float4*)(Bp + k0 + 40);
      q3 = *(const float4*)(Bp + k0 + 44);
    }

    bf16x8 af[4], bfr[4];
#pragma unroll
    for (int mi = 0; mi < 4; ++mi) {
      const int rowa = wr * 64 + mi * 16 + (lane & 15);
      af[mi] = *(const bf16x8*)(&As[lds_idx(rowa, lane >> 4)]);
    }
#pragma unroll
    for (int ni = 0; ni < 4; ++ni) {
      const int rowb = wc * 64 + ni * 16 + (lane & 15);
      bfr[ni] = *(const bf16x8*)(&Bs[lds_idx(rowb, lane >> 4)]);
    }
#pragma unroll
    for (int mi = 0; mi < 4; ++mi)
#pragma unroll
      for (int ni = 0; ni < 4; ++ni)
        acc[mi][ni] = __builtin_amdgcn_mfma_f32_16x16x32_bf16(af[mi], bfr[ni], acc[mi][ni], 0, 0, 0);
    __syncthreads();
  }

  // epilogue: C/D layout col=lane&15, row=(lane>>4)*4+reg   [m89 verified]
  const int r0 = bm + wr * 64 + ((lane >> 4) << 2);
  const int cc0 = bn + wc * 64 + (lane & 15);
#pragma unroll
  for (int mi = 0; mi < 4; ++mi)
#pragma unroll
    for (int ni = 0; ni < 4; ++ni) {
      const int col = cc0 + ni * 16;
      const float bv = bias[col];
#pragma unroll
      for (int r = 0; r < 4; ++r)
        C[(size_t)(r0 + mi * 16 + r) * N + col] = acc[mi][ni][r] + bv;
    }
}

// ---------------------------------------------------------------------------
// Attention scores: sc[s,b] = sum_d enc[s,b,d] * ht[b,d].
// ---------------------------------------------------------------------------
__global__ __launch_bounds__(64) void scores_kernel(
    const float* __restrict__ enc, const float* __restrict__ ht,
    float* __restrict__ sc)
{
  const int sb = blockIdx.x;
  const int b = sb % BATCH;
  const int lane = threadIdx.x;
  const float* e = enc + (size_t)sb * DH;
  const float* h = ht + (size_t)b * DH;
  float sum = 0.f;
  for (int k = lane * 4; k < DH; k += 64 * 4) {
    float4 ev = *reinterpret_cast<const float4*>(e + k);
    float4 hv = *reinterpret_cast<const float4*>(h + k);
    sum += ev.x * hv.x + ev.y * hv.y + ev.z * hv.z + ev.w * hv.w;
  }
#pragma unroll
  for (int off = 32; off; off >>= 1) sum += __shfl_down(sum, off);
  if (lane == 0) sc[sb] = sum;
}

// log_softmax over axis=1 (the BATCH dim) -- faithful to the reference.
__global__ __launch_bounds__(64) void logsoftmax_kernel(
    const float* __restrict__ sc, float* __restrict__ a)
{
  const int s = threadIdx.x;
  if (s >= SRC) return;
  const float* r = sc + (size_t)s * BATCH;
  float m = -INFINITY;
  for (int b = 0; b < BATCH; ++b) m = fmaxf(m, r[b]);
  float sum = 0.f;
  for (int b = 0; b < BATCH; ++b) sum += expf(r[b] - m);
  const float lse = m + logf(sum);
  float* o = a + (size_t)s * BATCH;
  for (int b = 0; b < BATCH; ++b) o[b] = r[b] - lse;
}

__global__ __launch_bounds__(256) void ctxsum_kernel(
    const float* __restrict__ a, const float* __restrict__ enc,
    const float* __restrict__ hidden, float* __restrict__ cat)
{
  const int b = blockIdx.x;
  const int d = blockIdx.y * 256 + threadIdx.x;
  float sum = 0.f;
  for (int s = 0; s < SRC; ++s)
    sum = fmaf(a[s * BATCH + b], enc[(size_t)(s * BATCH + b) * DH + d], sum);
  cat[(size_t)b * (2 * DH) + d] = sum;
  cat[(size_t)b * (2 * DH) + DH + d] = hidden[(size_t)b * DH + d];
}

__global__ __launch_bounds__(256) void gather_kernel(
    const int* __restrict__ targ, const float* __restrict__ emb,
    float* __restrict__ embedded)
{
  const int tb = blockIdx.x;
  const int tok = targ[tb];
  const float* src = emb + (size_t)tok * EMB;
  float* dst = embedded + (size_t)tb * EMB;
  for (int j = threadIdx.x; j < EMB; j += blockDim.x) dst[j] = src[j];
}

// ---------------------------------------------------------------------------
// Pack w_hh (fp32 [4096,1024]) -> bf16 MFMA B-frag layout:
// wpack[((jt*4+g)*32+k0)*64+l][8] = w_hh[g*1024+jt*16+(l&15)][k0*32+(l>>4)*8+e]
// ---------------------------------------------------------------------------
__global__ __launch_bounds__(64) void pack_whh_kernel(
    const float* __restrict__ w_hh, u16* __restrict__ wpack)
{
  const int bid = blockIdx.x;           // 64*4*32 = 8192 blocks
  const int k0 = bid & 31;
  const int g = (bid >> 5) & 3;
  const int jt = bid >> 7;
  const int l = threadIdx.x;
  const int row = g * 1024 + jt * 16 + (l & 15);
  const int col = k0 * 32 + (l >> 4) * 8;
  const float* src = w_hh + (size_t)row * DH + col;
  u16* dst = wpack + ((size_t)bid * 64 + l) * 8;
  uint4 w;
  float4 s0 = *(const float4*)(src);
  float4 s1 = *(const float4*)(src + 4);
  w.x = pack2bf(s0.x, s0.y); w.y = pack2bf(s0.z, s0.w);
  w.z = pack2bf(s1.x, s1.y); w.w = pack2bf(s1.z, s1.w);
  *(uint4*)dst = w;
}

// ---------------------------------------------------------------------------
// Fused MFMA LSTM step.  grid = 64 blocks (j-tiles of 16), 256 thr = 4 waves.
// Wave g computes gates[48, jt*16..+16] for gate g via MFMA over K=1024:
//   gates = h_prev(bf16,packed) @ w_hh(bf16,packed)^T     (fp32 accum)
// Gates exchanged via LDS; act phase fuses xg+ctxpart+activations and writes
// c (fp32), h (bf16 A-frag-packed for next step), hs slice (bf16 row-major).
// ---------------------------------------------------------------------------
template<int FIRST>
__global__ __launch_bounds__(256) void lstm_step_mfma(
    const u16* __restrict__ wpack,      // [64][4][32][64][8] bf16
    const u16* __restrict__ hpack_in,   // [3][32][64][8] bf16 (prev h)
    const float* __restrict__ xg_t,     // [48, 4096]
    const float* __restrict__ ctxpart,  // [48, 4096]
    float* __restrict__ c_buf,          // [48, 1024] fp32
    u16* __restrict__ hpack_out,        // [3][32][64][8] bf16
    u16* __restrict__ hs_t)             // [48, 1024] bf16 row-major
{
  __shared__ float gate_s[4][48][16];
  const int jt = blockIdx.x;
  const int tid = threadIdx.x;
  const int l = tid & 63;
  const int g = tid >> 6;

  if (!FIRST) {
    f32x4 acc0 = {0.f, 0.f, 0.f, 0.f};
    f32x4 acc1 = {0.f, 0.f, 0.f, 0.f};
    f32x4 acc2 = {0.f, 0.f, 0.f, 0.f};
    const u16* wp = wpack + (((size_t)(jt * 4 + g) * 32) * 64 + l) * 8;
    const u16* hp = hpack_in + (size_t)l * 8;
#pragma unroll 8
    for (int k0 = 0; k0 < 32; ++k0) {
      bf16x8 bfrag = *(const bf16x8*)(wp + (size_t)k0 * 512);
      bf16x8 a0 = *(const bf16x8*)(hp + (size_t)(0 * 32 + k0) * 512);
      bf16x8 a1 = *(const bf16x8*)(hp + (size_t)(1 * 32 + k0) * 512);
      bf16x8 a2 = *(const bf16x8*)(hp + (size_t)(2 * 32 + k0) * 512);
      acc0 = __builtin_amdgcn_mfma_f32_16x16x32_bf16(a0, bfrag, acc0, 0, 0, 0);
      acc1 = __builtin_amdgcn_mfma_f32_16x16x32_bf16(a1, bfrag, acc1, 0, 0, 0);
      acc2 = __builtin_amdgcn_mfma_f32_16x16x32_bf16(a2, bfrag, acc2, 0, 0, 0);
    }
    const int rr = (l >> 4) << 2;
    const int cc = l & 15;
#pragma unroll
    for (int r = 0; r < 4; ++r) {
      gate_s[g][ 0 + rr + r][cc] = acc0[r];
      gate_s[g][16 + rr + r][cc] = acc1[r];
      gate_s[g][32 + rr + r][cc] = acc2[r];
    }
  }
  __syncthreads();

#pragma unroll
  for (int p = 0; p < 3; ++p) {
    const int idx = p * 256 + tid;      // 0..767
    const int b = idx >> 4;
    const int j16 = idx & 15;
    const int j = jt * 16 + j16;
    const size_t xb = (size_t)b * GDIM + j;
    float gi = xg_t[xb + 0 * DH] + ctxpart[xb + 0 * DH];
    float gf = xg_t[xb + 1 * DH] + ctxpart[xb + 1 * DH];
    float gg = xg_t[xb + 2 * DH] + ctxpart[xb + 2 * DH];
    float go = xg_t[xb + 3 * DH] + ctxpart[xb + 3 * DH];
    if (!FIRST) {
      gi += gate_s[0][b][j16];
      gf += gate_s[1][b][j16];
      gg += gate_s[2][b][j16];
      go += gate_s[3][b][j16];
    }
    const float si = 1.f / (1.f + expf(-gi));
    const float sf = 1.f / (1.f + expf(-gf));
    const float so = 1.f / (1.f + expf(-go));
    const float tg = tanhf(gg);
    const float cp = FIRST ? 0.f : c_buf[b * DH + j];
    const float c = sf * cp + si * tg;
    const float h = so * tanhf(c);
    c_buf[b * DH + j] = c;
    const u16 hb = f2bf(h);
    hs_t[(size_t)b * DH + j] = hb;
    // h_pack position: mi=b>>4, r=b&15, k0=j>>5, sub=(j&31)>>3, e=j&7
    const int mi = b >> 4, r = b & 15;
    const int k0 = j >> 5, sub = (j & 31) >> 3, e = j & 7;
    hpack_out[((size_t)((mi * 32 + k0) * 64) + sub * 16 + r) * 8 + e] = hb;
  }
}

// ---------------------------------------------------------------------------
extern "C" void kernel_launch(void* const* d_in, const int* in_sizes, int n_in,
                              void* d_out, int out_size, void* d_ws, size_t ws_size,
                              hipStream_t stream) {
  const int*   targ     = (const int*)d_in[0];
  const float* enc      = (const float*)d_in[1];
  const float* emb      = (const float*)d_in[2];
  const float* attin_w  = (const float*)d_in[3];
  const float* attin_b  = (const float*)d_in[4];
  const float* attout_w = (const float*)d_in[5];
  const float* attout_b = (const float*)d_in[6];
  const float* gen_w    = (const float*)d_in[7];
  const float* gen_b    = (const float*)d_in[8];
  const float* hidden   = (const float*)d_in[9];
  const float* w_ih     = (const float*)d_in[10];
  const float* w_hh     = (const float*)d_in[11];
  const float* b_ih     = (const float*)d_in[12];
  const float* b_hh     = (const float*)d_in[13];
  float* out = (float*)d_out;

  // workspace carve (~70 MB)
  char* wsp = (char*)d_ws;
  auto alloc = [&](size_t bytes) {
    char* p = wsp;
    wsp += (bytes + 255) & ~(size_t)255;
    return p;
  };
  float* ht       = (float*)alloc((size_t)BATCH * DH * 4);
  float* sc       = (float*)alloc((size_t)SRC * BATCH * 4);
  float* attn     = (float*)alloc((size_t)SRC * BATCH * 4);
  float* cat      = (float*)alloc((size_t)BATCH * 2 * DH * 4);
  float* ctx      = (float*)alloc((size_t)BATCH * DH * 4);
  float* ctxpart  = (float*)alloc((size_t)BATCH * GDIM * 4);
  float* embedded = (float*)alloc((size_t)T_LEN * BATCH * EMB * 4);
  float* xg       = (float*)alloc((size_t)T_LEN * BATCH * GDIM * 4);
  float* cbuf     = (float*)alloc((size_t)BATCH * DH * 4);
  u16*   wpack    = (u16*)alloc((size_t)GDIM * DH * 2);
  u16*   hpack0   = (u16*)alloc((size_t)3 * 32 * 64 * 8 * 2);
  u16*   hpack1   = (u16*)alloc((size_t)3 * 32 * 64 * 8 * 2);
  u16*   hs_bf16  = (u16*)alloc((size_t)T_LEN * BATCH * DH * 2);

  // 0. pack w_hh -> bf16 MFMA layout (once per launch)
  pack_whh_kernel<<<64 * 4 * 32, 64, 0, stream>>>(w_hh, wpack);

  // 1. ht = hidden @ attin_w^T + attin_b            [48,1024]
  gemm_abt<0><<<dim3(1, DH / BN), 256, 0, stream>>>(
      hidden, DH, attin_w, DH, attin_b, nullptr, ht, DH, BATCH, DH, DH);

  // 2. sc[s,b] = enc[s,b,:] . ht[b,:]
  scores_kernel<<<SRC * BATCH, 64, 0, stream>>>(enc, ht, sc);

  // 3. a = log_softmax(sc, axis=1)  (over batch dim)
  logsoftmax_kernel<<<1, 64, 0, stream>>>(sc, attn);

  // 4. cat = [sum_s a*enc , hidden]                 [48,2048]
  ctxsum_kernel<<<dim3(BATCH, DH / 256), 256, 0, stream>>>(attn, enc, hidden, cat);

  // 5. context = tanh(cat @ attout_w^T + attout_b)  [48,1024]
  gemm_abt<1><<<dim3(1, DH / BN), 256, 0, stream>>>(
      cat, 2 * DH, attout_w, 2 * DH, attout_b, nullptr, ctx, DH, BATCH, DH, 2 * DH);

  // 6. ctxpart = context @ w_ih[:, :1024]^T + b_ih + b_hh   [48,4096]
  gemm_abt<0><<<dim3(1, GDIM / BN), 256, 0, stream>>>(
      ctx, DH, w_ih, XDIM, b_ih, b_hh, ctxpart, GDIM, BATCH, GDIM, DH);

  // 7. embedded = emb[targ]                          [3072,300]
  gather_kernel<<<T_LEN * BATCH, 256, 0, stream>>>(targ, emb, embedded);

  // 8. xg = embedded @ w_ih[:, 1024:]^T              [3072,4096]
  gemm_abt<0><<<dim3(T_LEN * BATCH / BM, GDIM / BN), 256, 0, stream>>>(
      embedded, EMB, w_ih + DH, XDIM, nullptr, nullptr, xg, GDIM,
      T_LEN * BATCH, GDIM, EMB);

  // 9. LSTM over 64 steps: one fused MFMA kernel per step
  for (int t = 0; t < T_LEN; ++t) {
    u16* hpw = (t & 1) ? hpack1 : hpack0;       // write
    u16* hpr = (t & 1) ? hpack0 : hpack1;       // read (= write of t-1)
    u16* hst = hs_bf16 + (size_t)t * BATCH * DH;
    const float* xgt = xg + (size_t)t * BATCH * GDIM;
    if (t == 0)
      lstm_step_mfma<1><<<64, 256, 0, stream>>>(wpack, hpr, xgt, ctxpart,
                                                cbuf, hpw, hst);
    else
      lstm_step_mfma<0><<<64, 256, 0, stream>>>(wpack, hpr, xgt, ctxpart,
                                                cbuf, hpw, hst);
  }

  // 10. out = hs(bf16) @ gen_w^T + gen_b   [3072,32000]  (MFMA, XCD-chunked)
  gemm_bf16_mfma<<<(T_LEN * BATCH / 128) * (VOC / 128), 256, 0, stream>>>(
      hs_bf16, gen_w, gen_b, out, T_LEN * BATCH, VOC, DH);
}

// Round 7
// 2110.204 us; speedup vs baseline: 7.1074x; 1.0883x over previous
//
#include <hip/hip_runtime.h>
#include <hip/hip_bf16.h>
#include <math.h>

// Decoder: T=64, B=48, S=64, D=1024, E=300, V=32000
#define T_LEN 64
#define BATCH 48
#define SRC   64
#define DH    1024
#define EMB   300
#define VOC   32000
#define GDIM  4096   // 4*DH
#define XDIM  1324   // DH+EMB
#define NBLK_L 64    // persistent LSTM blocks

typedef unsigned short u16;
typedef __attribute__((ext_vector_type(8))) short bf16x8;
typedef __attribute__((ext_vector_type(4))) float f32x4;

__device__ inline u16 f2bf(float f) {
  unsigned u = __float_as_uint(f);
  unsigned r = u + 0x7FFFu + ((u >> 16) & 1u);   // RNE
  return (u16)(r >> 16);
}
__device__ inline unsigned pack2bf(float lo, float hi) {
  return (unsigned)f2bf(lo) | ((unsigned)f2bf(hi) << 16);
}

__device__ inline void gload_lds16(const void* g, void* l) {
  __builtin_amdgcn_global_load_lds(
      (const __attribute__((address_space(1))) void*)g,
      (__attribute__((address_space(3))) void*)l, 16, 0, 0);
}

// ---------------------------------------------------------------------------
// Generic fp32 GEMM: C[M,N] = A[M,K]*B[N,K]^T (+bias0+bias1)(+rowadd)[+tanh]
// ---------------------------------------------------------------------------
#define BM 128
#define BN 128
#define BK 8

template<int ACT>
__global__ __launch_bounds__(256, 2) void gemm_abt(
    const float* __restrict__ A, int lda,
    const float* __restrict__ B, int ldb,
    const float* __restrict__ bias0, const float* __restrict__ bias1,
    const float* __restrict__ rowadd, int rowmod,
    float* __restrict__ C, int ldc, int M, int N, int K)
{
  __shared__ float As[BK][BM + 4];
  __shared__ float Bs[BK][BN + 4];
  const int tid = threadIdx.x;
  const int bm = blockIdx.x * BM;
  const int bn = blockIdx.y * BN;
  const int tr = (tid >> 4) << 3;
  const int tc = (tid & 15) << 3;

  float acc[8][8];
#pragma unroll
  for (int i = 0; i < 8; ++i)
#pragma unroll
    for (int j = 0; j < 8; ++j) acc[i][j] = 0.f;

  const int lrow = tid >> 1;
  const int lcol = (tid & 1) << 2;

  for (int k0 = 0; k0 < K; k0 += BK) {
    float4 av = make_float4(0.f, 0.f, 0.f, 0.f);
    {
      const int gr = bm + lrow;
      if (gr < M) {
        if (k0 + BK <= K) {
          av = *reinterpret_cast<const float4*>(A + (size_t)gr * lda + k0 + lcol);
        } else {
          float t0 = 0.f, t1 = 0.f, t2 = 0.f, t3 = 0.f;
          const int kk = k0 + lcol;
          if (kk + 0 < K) t0 = A[(size_t)gr * lda + kk + 0];
          if (kk + 1 < K) t1 = A[(size_t)gr * lda + kk + 1];
          if (kk + 2 < K) t2 = A[(size_t)gr * lda + kk + 2];
          if (kk + 3 < K) t3 = A[(size_t)gr * lda + kk + 3];
          av = make_float4(t0, t1, t2, t3);
        }
      }
    }
    float4 bv = make_float4(0.f, 0.f, 0.f, 0.f);
    {
      const int gr = bn + lrow;
      if (gr < N) {
        if (k0 + BK <= K) {
          bv = *reinterpret_cast<const float4*>(B + (size_t)gr * ldb + k0 + lcol);
        } else {
          float t0 = 0.f, t1 = 0.f, t2 = 0.f, t3 = 0.f;
          const int kk = k0 + lcol;
          if (kk + 0 < K) t0 = B[(size_t)gr * ldb + kk + 0];
          if (kk + 1 < K) t1 = B[(size_t)gr * ldb + kk + 1];
          if (kk + 2 < K) t2 = B[(size_t)gr * ldb + kk + 2];
          if (kk + 3 < K) t3 = B[(size_t)gr * ldb + kk + 3];
          bv = make_float4(t0, t1, t2, t3);
        }
      }
    }
    As[lcol + 0][lrow] = av.x; As[lcol + 1][lrow] = av.y;
    As[lcol + 2][lrow] = av.z; As[lcol + 3][lrow] = av.w;
    Bs[lcol + 0][lrow] = bv.x; Bs[lcol + 1][lrow] = bv.y;
    Bs[lcol + 2][lrow] = bv.z; Bs[lcol + 3][lrow] = bv.w;
    __syncthreads();

#pragma unroll
    for (int k = 0; k < BK; ++k) {
      float a[8], b[8];
      *reinterpret_cast<float4*>(&a[0]) = *reinterpret_cast<const float4*>(&As[k][tr]);
      *reinterpret_cast<float4*>(&a[4]) = *reinterpret_cast<const float4*>(&As[k][tr + 4]);
      *reinterpret_cast<float4*>(&b[0]) = *reinterpret_cast<const float4*>(&Bs[k][tc]);
      *reinterpret_cast<float4*>(&b[4]) = *reinterpret_cast<const float4*>(&Bs[k][tc + 4]);
#pragma unroll
      for (int i = 0; i < 8; ++i)
#pragma unroll
        for (int j = 0; j < 8; ++j) acc[i][j] = fmaf(a[i], b[j], acc[i][j]);
    }
    __syncthreads();
  }

#pragma unroll
  for (int i = 0; i < 8; ++i) {
    const int gr = bm + tr + i;
    if (gr >= M) break;
#pragma unroll
    for (int j = 0; j < 8; ++j) {
      const int gc = bn + tc + j;
      if (gc >= N) continue;
      float v = acc[i][j];
      if (bias0) v += bias0[gc];
      if (bias1) v += bias1[gc];
      if (rowadd) v += rowadd[(size_t)(gr % rowmod) * ldc + gc];
      if (ACT == 1) v = tanhf(v);
      C[(size_t)gr * ldc + gc] = v;
    }
  }
}

// ---------------------------------------------------------------------------
// LDS swizzle shared by MFMA GEMMs: 64B rows, 16B chunks,
// chunk' = chunk ^ ((row>>1)&3)  -> 2-way max bank aliasing (free, m136)
// ---------------------------------------------------------------------------
__device__ inline int lds_idx(int row, int chunk) {
  return row * 32 + ((chunk ^ ((row >> 1) & 3)) << 3);   // u16 units
}

// ---------------------------------------------------------------------------
// Fallback bf16 MFMA GEMM (B fp32, converted at stage) -- round-6 verified.
// ---------------------------------------------------------------------------
__global__ __launch_bounds__(256) void gemm_bf16_mfma(
    const u16* __restrict__ A, const float* __restrict__ B,
    const float* __restrict__ bias, float* __restrict__ C, int M, int N, int K)
{
  __shared__ u16 As[128 * 32];
  __shared__ u16 Bs[128 * 32];
  const int tid = threadIdx.x;
  const int lane = tid & 63;
  const int wv = tid >> 6;
  const int wr = wv >> 1, wc = wv & 1;

  const int nmt = M >> 7;
  const int chunk_sz = (int)gridDim.x >> 3;
  const int bid = (int)blockIdx.x;
  const int wg = (bid & 7) * chunk_sz + (bid >> 3);
  const int bm = (wg % nmt) * 128;
  const int bn = (wg / nmt) * 128;

  const int srow = tid >> 1;
  const int c0 = (tid & 1) << 1;

  const u16*  Ap = A + (size_t)(bm + srow) * K + (c0 << 3);
  const float* Bp = B + (size_t)(bn + srow) * K + (c0 << 3);

  f32x4 acc[4][4];
#pragma unroll
  for (int i = 0; i < 4; ++i)
#pragma unroll
    for (int j = 0; j < 4; ++j) acc[i][j] = (f32x4){0.f, 0.f, 0.f, 0.f};

  f32x4 a0 = *(const f32x4*)(Ap);
  f32x4 a1 = *(const f32x4*)(Ap + 8);
  float4 q0 = *(const float4*)(Bp);
  float4 q1 = *(const float4*)(Bp + 4);
  float4 q2 = *(const float4*)(Bp + 8);
  float4 q3 = *(const float4*)(Bp + 12);

  for (int k0 = 0; k0 < K; k0 += 32) {
    *(f32x4*)(&As[lds_idx(srow, c0)]) = a0;
    *(f32x4*)(&As[lds_idx(srow, c0 + 1)]) = a1;
    uint4 w0, w1;
    w0.x = pack2bf(q0.x, q0.y); w0.y = pack2bf(q0.z, q0.w);
    w0.z = pack2bf(q1.x, q1.y); w0.w = pack2bf(q1.z, q1.w);
    w1.x = pack2bf(q2.x, q2.y); w1.y = pack2bf(q2.z, q2.w);
    w1.z = pack2bf(q3.x, q3.y); w1.w = pack2bf(q3.z, q3.w);
    *(uint4*)(&Bs[lds_idx(srow, c0)]) = w0;
    *(uint4*)(&Bs[lds_idx(srow, c0 + 1)]) = w1;
    __syncthreads();

    if (k0 + 32 < K) {
      a0 = *(const f32x4*)(Ap + k0 + 32);
      a1 = *(const f32x4*)(Ap + k0 + 40);
      q0 = *(const float4*)(Bp + k0 + 32);
      q1 = *(const float4*)(Bp + k0 + 36);
      q2 = *(const float4*)(Bp + k0 + 40);
      q3 = *(const float4*)(Bp + k0 + 44);
    }

    bf16x8 af[4], bfr[4];
#pragma unroll
    for (int mi = 0; mi < 4; ++mi)
      af[mi] = *(const bf16x8*)(&As[lds_idx(wr * 64 + mi * 16 + (lane & 15), lane >> 4)]);
#pragma unroll
    for (int ni = 0; ni < 4; ++ni)
      bfr[ni] = *(const bf16x8*)(&Bs[lds_idx(wc * 64 + ni * 16 + (lane & 15), lane >> 4)]);
#pragma unroll
    for (int mi = 0; mi < 4; ++mi)
#pragma unroll
      for (int ni = 0; ni < 4; ++ni)
        acc[mi][ni] = __builtin_amdgcn_mfma_f32_16x16x32_bf16(af[mi], bfr[ni], acc[mi][ni], 0, 0, 0);
    __syncthreads();
  }

  const int r0 = bm + wr * 64 + ((lane >> 4) << 2);
  const int cc0 = bn + wc * 64 + (lane & 15);
#pragma unroll
  for (int mi = 0; mi < 4; ++mi)
#pragma unroll
    for (int ni = 0; ni < 4; ++ni) {
      const int col = cc0 + ni * 16;
      const float bv = bias[col];
#pragma unroll
      for (int r = 0; r < 4; ++r)
        C[(size_t)(r0 + mi * 16 + r) * N + col] = acc[mi][ni][r] + bv;
    }
}

// ---------------------------------------------------------------------------
// m97-structure GEMM: both operands bf16, global_load_lds width=16,
// pre-swizzled global source + lds_idx reads (linear LDS dest).
// ---------------------------------------------------------------------------
__global__ __launch_bounds__(256) void gemm_bf16x2_mfma(
    const u16* __restrict__ A, const u16* __restrict__ B,
    const float* __restrict__ bias, float* __restrict__ C, int M, int N, int K)
{
  __shared__ u16 As[128 * 32];
  __shared__ u16 Bs[128 * 32];
  const int tid = threadIdx.x;
  const int lane = tid & 63;
  const int wv = tid >> 6;
  const int wr = wv >> 1, wc = wv & 1;

  const int nmt = M >> 7;
  const int chunk_sz = (int)gridDim.x >> 3;
  const int bid = (int)blockIdx.x;
  const int wg = (bid & 7) * chunk_sz + (bid >> 3);
  const int bm = (wg % nmt) * 128;
  const int bn = (wg / nmt) * 128;

  // staging: 16 segments of 1KB (A segs 0-7, B segs 8-15); wave wv owns 4.
  const int rseg = lane >> 2;     // row within 16-row segment
  const int cch = lane & 3;       // raw 16B chunk
  const u16* gsrc[4];
  u16* ldst[4];
#pragma unroll
  for (int i = 0; i < 4; ++i) {
    const int s = wv * 4 + i;
    const int row = (s & 7) * 16 + rseg;          // tile row 0..127
    const int ch = cch ^ ((row >> 1) & 3);        // pre-swizzle (inverse of lds_idx)
    if (s < 8) {
      gsrc[i] = A + (size_t)(bm + row) * K + ch * 8;
      ldst[i] = &As[s * 512];
    } else {
      gsrc[i] = B + (size_t)(bn + row) * K + ch * 8;
      ldst[i] = &Bs[(s - 8) * 512];
    }
  }

  f32x4 acc[4][4];
#pragma unroll
  for (int i = 0; i < 4; ++i)
#pragma unroll
    for (int j = 0; j < 4; ++j) acc[i][j] = (f32x4){0.f, 0.f, 0.f, 0.f};

  for (int k0 = 0; k0 < K; k0 += 32) {
#pragma unroll
    for (int i = 0; i < 4; ++i)
      gload_lds16(gsrc[i] + k0, ldst[i]);
    __syncthreads();                 // drains vmcnt before barrier

    bf16x8 af[4], bfr[4];
#pragma unroll
    for (int mi = 0; mi < 4; ++mi)
      af[mi] = *(const bf16x8*)(&As[lds_idx(wr * 64 + mi * 16 + (lane & 15), lane >> 4)]);
#pragma unroll
    for (int ni = 0; ni < 4; ++ni)
      bfr[ni] = *(const bf16x8*)(&Bs[lds_idx(wc * 64 + ni * 16 + (lane & 15), lane >> 4)]);
#pragma unroll
    for (int mi = 0; mi < 4; ++mi)
#pragma unroll
      for (int ni = 0; ni < 4; ++ni)
        acc[mi][ni] = __builtin_amdgcn_mfma_f32_16x16x32_bf16(af[mi], bfr[ni], acc[mi][ni], 0, 0, 0);
    __syncthreads();
  }

  const int r0 = bm + wr * 64 + ((lane >> 4) << 2);
  const int cc0 = bn + wc * 64 + (lane & 15);
#pragma unroll
  for (int mi = 0; mi < 4; ++mi)
#pragma unroll
    for (int ni = 0; ni < 4; ++ni) {
      const int col = cc0 + ni * 16;
      const float bv = bias[col];
#pragma unroll
      for (int r = 0; r < 4; ++r)
        C[(size_t)(r0 + mi * 16 + r) * N + col] = acc[mi][ni][r] + bv;
    }
}

// ---------------------------------------------------------------------------
// gen_w fp32 -> bf16 (same layout), 8 elems/thread
// ---------------------------------------------------------------------------
__global__ __launch_bounds__(256) void cvt_f32_bf16_kernel(
    const float* __restrict__ src, u16* __restrict__ dst, int n8)
{
  const int i = blockIdx.x * 256 + threadIdx.x;
  if (i >= n8) return;
  const float4 s0 = ((const float4*)src)[2 * i];
  const float4 s1 = ((const float4*)src)[2 * i + 1];
  uint4 w;
  w.x = pack2bf(s0.x, s0.y); w.y = pack2bf(s0.z, s0.w);
  w.z = pack2bf(s1.x, s1.y); w.w = pack2bf(s1.z, s1.w);
  ((uint4*)dst)[i] = w;
}

// ---------------------------------------------------------------------------
// Attention / misc small kernels (unchanged from round 6)
// ---------------------------------------------------------------------------
__global__ __launch_bounds__(64) void scores_kernel(
    const float* __restrict__ enc, const float* __restrict__ ht,
    float* __restrict__ sc)
{
  const int sb = blockIdx.x;
  const int b = sb % BATCH;
  const int lane = threadIdx.x;
  const float* e = enc + (size_t)sb * DH;
  const float* h = ht + (size_t)b * DH;
  float sum = 0.f;
  for (int k = lane * 4; k < DH; k += 64 * 4) {
    float4 ev = *reinterpret_cast<const float4*>(e + k);
    float4 hv = *reinterpret_cast<const float4*>(h + k);
    sum += ev.x * hv.x + ev.y * hv.y + ev.z * hv.z + ev.w * hv.w;
  }
#pragma unroll
  for (int off = 32; off; off >>= 1) sum += __shfl_down(sum, off);
  if (lane == 0) sc[sb] = sum;
}

__global__ __launch_bounds__(64) void logsoftmax_kernel(
    const float* __restrict__ sc, float* __restrict__ a)
{
  const int s = threadIdx.x;
  if (s >= SRC) return;
  const float* r = sc + (size_t)s * BATCH;
  float m = -INFINITY;
  for (int b = 0; b < BATCH; ++b) m = fmaxf(m, r[b]);
  float sum = 0.f;
  for (int b = 0; b < BATCH; ++b) sum += expf(r[b] - m);
  const float lse = m + logf(sum);
  float* o = a + (size_t)s * BATCH;
  for (int b = 0; b < BATCH; ++b) o[b] = r[b] - lse;
}

__global__ __launch_bounds__(256) void ctxsum_kernel(
    const float* __restrict__ a, const float* __restrict__ enc,
    const float* __restrict__ hidden, float* __restrict__ cat)
{
  const int b = blockIdx.x;
  const int d = blockIdx.y * 256 + threadIdx.x;
  float sum = 0.f;
  for (int s = 0; s < SRC; ++s)
    sum = fmaf(a[s * BATCH + b], enc[(size_t)(s * BATCH + b) * DH + d], sum);
  cat[(size_t)b * (2 * DH) + d] = sum;
  cat[(size_t)b * (2 * DH) + DH + d] = hidden[(size_t)b * DH + d];
}

__global__ __launch_bounds__(256) void gather_kernel(
    const int* __restrict__ targ, const float* __restrict__ emb,
    float* __restrict__ embedded)
{
  const int tb = blockIdx.x;
  const int tok = targ[tb];
  const float* src = emb + (size_t)tok * EMB;
  float* dst = embedded + (size_t)tb * EMB;
  for (int j = threadIdx.x; j < EMB; j += blockDim.x) dst[j] = src[j];
}

// ---------------------------------------------------------------------------
// Pack w_hh -> bf16 MFMA B-frag layout (round 6, verified)
// ---------------------------------------------------------------------------
__global__ __launch_bounds__(64) void pack_whh_kernel(
    const float* __restrict__ w_hh, u16* __restrict__ wpack)
{
  const int bid = blockIdx.x;           // 8192
  const int k0 = bid & 31;
  const int g = (bid >> 5) & 3;
  const int jt = bid >> 7;
  const int l = threadIdx.x;
  const int row = g * 1024 + jt * 16 + (l & 15);
  const int col = k0 * 32 + (l >> 4) * 8;
  const float* src = w_hh + (size_t)row * DH + col;
  u16* dst = wpack + ((size_t)bid * 64 + l) * 8;
  uint4 w;
  float4 s0 = *(const float4*)(src);
  float4 s1 = *(const float4*)(src + 4);
  w.x = pack2bf(s0.x, s0.y); w.y = pack2bf(s0.z, s0.w);
  w.z = pack2bf(s1.x, s1.y); w.w = pack2bf(s1.z, s1.w);
  *(uint4*)dst = w;
}

__global__ void init_bar_kernel(unsigned* bar) {
  if (threadIdx.x < 8) bar[threadIdx.x] = 0u;
}

// ---------------------------------------------------------------------------
// Persistent LSTM: ONE launch, 64 blocks x 768 thr (12 waves = 4 gates x 3
// m-tiles).  Per step: MFMA gates GEMM (h bf16-packed, w_hh bf16-packed, fp32
// accum) -> LDS exchange -> fused act (c in registers) -> h/hs writes ->
// device-wide barrier (cumulative atomic count + agent fences, G16).
// xg already contains ctxpart + biases (folded in xg GEMM epilogue).
// ---------------------------------------------------------------------------
__global__ __launch_bounds__(768, 1) void lstm_persistent(
    const u16* __restrict__ wpack,      // [64][4][32][64][8]
    const float* __restrict__ xg,       // [T*48, 4096], ctx+biases folded
    u16* __restrict__ hbuf0, u16* __restrict__ hbuf1,  // packed [3][32][64][8]
    u16* __restrict__ hs,               // [T][48][1024] row-major
    unsigned* bar)
{
  __shared__ float gate_s[4][48][16];
  const int jt = (int)blockIdx.x;       // 0..63
  const int tid = (int)threadIdx.x;
  const int l = tid & 63;
  const int wv = tid >> 6;              // 0..11
  const int g = wv & 3;
  const int mi = wv >> 2;               // 0..2
  const int ab = tid >> 4;              // act: batch 0..47
  const int aj = tid & 15;              // act: j within tile
  const int ajj = jt * 16 + aj;
  float c_reg = 0.f;

  const u16* wp = wpack + (((size_t)(jt * 4 + g) * 32) * 64 + l) * 8;
  // packed-h write offset for act thread (ab, ajj)
  const int w_mi = ab >> 4, w_r = ab & 15;
  const int w_k0 = ajj >> 5, w_sub = (ajj & 31) >> 3, w_e = ajj & 7;
  const size_t w_off =
      ((size_t)((w_mi * 32 + w_k0) * 64) + w_sub * 16 + w_r) * 8 + w_e;

  for (int t = 0; t < T_LEN; ++t) {
    if (t > 0) {
      const u16* hp = (t & 1) ? hbuf0 : hbuf1;   // h(t-1) = buf[(t-1)&1]
      const u16* hpm = hp + ((size_t)(mi * 32) * 64 + l) * 8;
      f32x4 acc = {0.f, 0.f, 0.f, 0.f};
#pragma unroll 8
      for (int k0 = 0; k0 < 32; ++k0) {
        bf16x8 bfrag = *(const bf16x8*)(wp + (size_t)k0 * 512);
        bf16x8 afrag = *(const bf16x8*)(hpm + (size_t)k0 * 512);
        acc = __builtin_amdgcn_mfma_f32_16x16x32_bf16(afrag, bfrag, acc, 0, 0, 0);
      }
      const int rr = (l >> 4) << 2;
      const int cc = l & 15;
#pragma unroll
      for (int r = 0; r < 4; ++r)
        gate_s[g][mi * 16 + rr + r][cc] = acc[r];
    }
    __syncthreads();

    // act: thread == one (b, j)
    {
      const size_t xb = ((size_t)t * BATCH + ab) * GDIM + ajj;
      float gi = xg[xb + 0 * DH];
      float gf = xg[xb + 1 * DH];
      float gg = xg[xb + 2 * DH];
      float go = xg[xb + 3 * DH];
      if (t > 0) {
        gi += gate_s[0][ab][aj];
        gf += gate_s[1][ab][aj];
        gg += gate_s[2][ab][aj];
        go += gate_s[3][ab][aj];
      }
      const float si = 1.f / (1.f + expf(-gi));
      const float sf = 1.f / (1.f + expf(-gf));
      const float so = 1.f / (1.f + expf(-go));
      const float tg = tanhf(gg);
      c_reg = sf * c_reg + si * tg;
      const float h = so * tanhf(c_reg);
      const u16 hb = f2bf(h);
      hs[(size_t)t * BATCH * DH + (size_t)ab * DH + ajj] = hb;
      u16* hw = (t & 1) ? hbuf1 : hbuf0;         // h(t) = buf[t&1]
      hw[w_off] = hb;
    }

    // device-wide barrier: all h(t) visible before any block's step t+1
    __syncthreads();                              // drains this block's stores
    if (tid == 0) {
      __threadfence();                            // agent release (wb L2)
      __hip_atomic_fetch_add(bar, 1u, __ATOMIC_RELEASE, __HIP_MEMORY_SCOPE_AGENT);
      const unsigned target = (unsigned)NBLK_L * (unsigned)(t + 1);
      while (__hip_atomic_load(bar, __ATOMIC_ACQUIRE, __HIP_MEMORY_SCOPE_AGENT) < target)
        __builtin_amdgcn_s_sleep(2);
      __threadfence();                            // agent acquire (inv caches)
    }
    __syncthreads();
  }
}

// ---------------------------------------------------------------------------
extern "C" void kernel_launch(void* const* d_in, const int* in_sizes, int n_in,
                              void* d_out, int out_size, void* d_ws, size_t ws_size,
                              hipStream_t stream) {
  const int*   targ     = (const int*)d_in[0];
  const float* enc      = (const float*)d_in[1];
  const float* emb      = (const float*)d_in[2];
  const float* attin_w  = (const float*)d_in[3];
  const float* attin_b  = (const float*)d_in[4];
  const float* attout_w = (const float*)d_in[5];
  const float* attout_b = (const float*)d_in[6];
  const float* gen_w    = (const float*)d_in[7];
  const float* gen_b    = (const float*)d_in[8];
  const float* hidden   = (const float*)d_in[9];
  const float* w_ih     = (const float*)d_in[10];
  const float* w_hh     = (const float*)d_in[11];
  const float* b_ih     = (const float*)d_in[12];
  const float* b_hh     = (const float*)d_in[13];
  float* out = (float*)d_out;

  char* wsp = (char*)d_ws;
  auto alloc = [&](size_t bytes) {
    char* p = wsp;
    wsp += (bytes + 255) & ~(size_t)255;
    return p;
  };
  float* ht       = (float*)alloc((size_t)BATCH * DH * 4);
  float* sc       = (float*)alloc((size_t)SRC * BATCH * 4);
  float* attn     = (float*)alloc((size_t)SRC * BATCH * 4);
  float* cat      = (float*)alloc((size_t)BATCH * 2 * DH * 4);
  float* ctx      = (float*)alloc((size_t)BATCH * DH * 4);
  float* ctxpart  = (float*)alloc((size_t)BATCH * GDIM * 4);
  float* embedded = (float*)alloc((size_t)T_LEN * BATCH * EMB * 4);
  float* xg       = (float*)alloc((size_t)T_LEN * BATCH * GDIM * 4);
  u16*   wpack    = (u16*)alloc((size_t)GDIM * DH * 2);
  u16*   hbuf0    = (u16*)alloc((size_t)3 * 32 * 64 * 8 * 2);
  u16*   hbuf1    = (u16*)alloc((size_t)3 * 32 * 64 * 8 * 2);
  u16*   hs_bf16  = (u16*)alloc((size_t)T_LEN * BATCH * DH * 2);
  unsigned* bar   = (unsigned*)alloc(256);
  u16*   genw_bf16 = (u16*)alloc((size_t)VOC * DH * 2);   // LAST (guarded)
  const bool bigB = (size_t)(wsp - (char*)d_ws) <= ws_size;

  // 0. one-off weight reshapes
  pack_whh_kernel<<<64 * 4 * 32, 64, 0, stream>>>(w_hh, wpack);
  if (bigB)
    cvt_f32_bf16_kernel<<<(VOC * DH / 8 + 255) / 256, 256, 0, stream>>>(
        gen_w, genw_bf16, VOC * DH / 8);

  // 1. ht = hidden @ attin_w^T + attin_b
  gemm_abt<0><<<dim3(1, DH / BN), 256, 0, stream>>>(
      hidden, DH, attin_w, DH, attin_b, nullptr, nullptr, 1, ht, DH, BATCH, DH, DH);

  // 2-4. scores, log_softmax(axis=batch), context sum
  scores_kernel<<<SRC * BATCH, 64, 0, stream>>>(enc, ht, sc);
  logsoftmax_kernel<<<1, 64, 0, stream>>>(sc, attn);
  ctxsum_kernel<<<dim3(BATCH, DH / 256), 256, 0, stream>>>(attn, enc, hidden, cat);

  // 5. context = tanh(cat @ attout_w^T + attout_b)
  gemm_abt<1><<<dim3(1, DH / BN), 256, 0, stream>>>(
      cat, 2 * DH, attout_w, 2 * DH, attout_b, nullptr, nullptr, 1, ctx, DH, BATCH, DH, 2 * DH);

  // 6. ctxpart = context @ w_ih[:, :1024]^T + b_ih + b_hh
  gemm_abt<0><<<dim3(1, GDIM / BN), 256, 0, stream>>>(
      ctx, DH, w_ih, XDIM, b_ih, b_hh, nullptr, 1, ctxpart, GDIM, BATCH, GDIM, DH);

  // 7. embedded = emb[targ]
  gather_kernel<<<T_LEN * BATCH, 256, 0, stream>>>(targ, emb, embedded);

  // 8. xg = embedded @ w_ih[:, 1024:]^T  (+ ctxpart folded per row b=gr%48)
  gemm_abt<0><<<dim3(T_LEN * BATCH / BM, GDIM / BN), 256, 0, stream>>>(
      embedded, EMB, w_ih + DH, XDIM, nullptr, nullptr, ctxpart, BATCH,
      xg, GDIM, T_LEN * BATCH, GDIM, EMB);

  // 9. persistent LSTM (single launch, device-wide barrier per step)
  init_bar_kernel<<<1, 64, 0, stream>>>(bar);
  lstm_persistent<<<NBLK_L, 768, 0, stream>>>(wpack, xg, hbuf0, hbuf1, hs_bf16, bar);

  // 10. out = hs @ gen_w^T + gen_b
  if (bigB)
    gemm_bf16x2_mfma<<<(T_LEN * BATCH / 128) * (VOC / 128), 256, 0, stream>>>(
        hs_bf16, genw_bf16, gen_b, out, T_LEN * BATCH, VOC, DH);
  else
    gemm_bf16_mfma<<<(T_LEN * BATCH / 128) * (VOC / 128), 256, 0, stream>>>(
        hs_bf16, gen_w, gen_b, out, T_LEN * BATCH, VOC, DH);
}

// Round 8
// 2063.392 us; speedup vs baseline: 7.2686x; 1.0227x over previous
//
#include <hip/hip_runtime.h>
#include <hip/hip_bf16.h>
#include <math.h>

// Decoder: T=64, B=48, S=64, D=1024, E=300, V=32000
#define T_LEN 64
#define BATCH 48
#define SRC   64
#define DH    1024
#define EMB   300
#define VOC   32000
#define GDIM  4096   // 4*DH
#define XDIM  1324   // DH+EMB
#define NBLK_L 64    // persistent LSTM blocks

typedef unsigned short u16;
typedef __attribute__((ext_vector_type(8))) short bf16x8;
typedef __attribute__((ext_vector_type(4))) float f32x4;

__device__ inline u16 f2bf(float f) {
  unsigned u = __float_as_uint(f);
  unsigned r = u + 0x7FFFu + ((u >> 16) & 1u);   // RNE
  return (u16)(r >> 16);
}
__device__ inline unsigned pack2bf(float lo, float hi) {
  return (unsigned)f2bf(lo) | ((unsigned)f2bf(hi) << 16);
}

__device__ inline void gload_lds16(const void* g, void* l) {
  __builtin_amdgcn_global_load_lds(
      (const __attribute__((address_space(1))) void*)g,
      (__attribute__((address_space(3))) void*)l, 16, 0, 0);
}

// ---------------------------------------------------------------------------
// Generic fp32 GEMM: C[M,N] = A[M,K]*B[N,K]^T (+bias0+bias1)(+rowadd)[+tanh]
// ---------------------------------------------------------------------------
#define BM 128
#define BN 128
#define BK 8

template<int ACT>
__global__ __launch_bounds__(256, 2) void gemm_abt(
    const float* __restrict__ A, int lda,
    const float* __restrict__ B, int ldb,
    const float* __restrict__ bias0, const float* __restrict__ bias1,
    const float* __restrict__ rowadd, int rowmod,
    float* __restrict__ C, int ldc, int M, int N, int K)
{
  __shared__ float As[BK][BM + 4];
  __shared__ float Bs[BK][BN + 4];
  const int tid = threadIdx.x;
  const int bm = blockIdx.x * BM;
  const int bn = blockIdx.y * BN;
  const int tr = (tid >> 4) << 3;
  const int tc = (tid & 15) << 3;

  float acc[8][8];
#pragma unroll
  for (int i = 0; i < 8; ++i)
#pragma unroll
    for (int j = 0; j < 8; ++j) acc[i][j] = 0.f;

  const int lrow = tid >> 1;
  const int lcol = (tid & 1) << 2;

  for (int k0 = 0; k0 < K; k0 += BK) {
    float4 av = make_float4(0.f, 0.f, 0.f, 0.f);
    {
      const int gr = bm + lrow;
      if (gr < M) {
        if (k0 + BK <= K) {
          av = *reinterpret_cast<const float4*>(A + (size_t)gr * lda + k0 + lcol);
        } else {
          float t0 = 0.f, t1 = 0.f, t2 = 0.f, t3 = 0.f;
          const int kk = k0 + lcol;
          if (kk + 0 < K) t0 = A[(size_t)gr * lda + kk + 0];
          if (kk + 1 < K) t1 = A[(size_t)gr * lda + kk + 1];
          if (kk + 2 < K) t2 = A[(size_t)gr * lda + kk + 2];
          if (kk + 3 < K) t3 = A[(size_t)gr * lda + kk + 3];
          av = make_float4(t0, t1, t2, t3);
        }
      }
    }
    float4 bv = make_float4(0.f, 0.f, 0.f, 0.f);
    {
      const int gr = bn + lrow;
      if (gr < N) {
        if (k0 + BK <= K) {
          bv = *reinterpret_cast<const float4*>(B + (size_t)gr * ldb + k0 + lcol);
        } else {
          float t0 = 0.f, t1 = 0.f, t2 = 0.f, t3 = 0.f;
          const int kk = k0 + lcol;
          if (kk + 0 < K) t0 = B[(size_t)gr * ldb + kk + 0];
          if (kk + 1 < K) t1 = B[(size_t)gr * ldb + kk + 1];
          if (kk + 2 < K) t2 = B[(size_t)gr * ldb + kk + 2];
          if (kk + 3 < K) t3 = B[(size_t)gr * ldb + kk + 3];
          bv = make_float4(t0, t1, t2, t3);
        }
      }
    }
    As[lcol + 0][lrow] = av.x; As[lcol + 1][lrow] = av.y;
    As[lcol + 2][lrow] = av.z; As[lcol + 3][lrow] = av.w;
    Bs[lcol + 0][lrow] = bv.x; Bs[lcol + 1][lrow] = bv.y;
    Bs[lcol + 2][lrow] = bv.z; Bs[lcol + 3][lrow] = bv.w;
    __syncthreads();

#pragma unroll
    for (int k = 0; k < BK; ++k) {
      float a[8], b[8];
      *reinterpret_cast<float4*>(&a[0]) = *reinterpret_cast<const float4*>(&As[k][tr]);
      *reinterpret_cast<float4*>(&a[4]) = *reinterpret_cast<const float4*>(&As[k][tr + 4]);
      *reinterpret_cast<float4*>(&b[0]) = *reinterpret_cast<const float4*>(&Bs[k][tc]);
      *reinterpret_cast<float4*>(&b[4]) = *reinterpret_cast<const float4*>(&Bs[k][tc + 4]);
#pragma unroll
      for (int i = 0; i < 8; ++i)
#pragma unroll
        for (int j = 0; j < 8; ++j) acc[i][j] = fmaf(a[i], b[j], acc[i][j]);
    }
    __syncthreads();
  }

#pragma unroll
  for (int i = 0; i < 8; ++i) {
    const int gr = bm + tr + i;
    if (gr >= M) break;
#pragma unroll
    for (int j = 0; j < 8; ++j) {
      const int gc = bn + tc + j;
      if (gc >= N) continue;
      float v = acc[i][j];
      if (bias0) v += bias0[gc];
      if (bias1) v += bias1[gc];
      if (rowadd) v += rowadd[(size_t)(gr % rowmod) * ldc + gc];
      if (ACT == 1) v = tanhf(v);
      C[(size_t)gr * ldc + gc] = v;
    }
  }
}

// ---------------------------------------------------------------------------
// LDS swizzle shared by MFMA GEMMs: 64B rows, 16B chunks,
// chunk' = chunk ^ ((row>>1)&3)  -> 2-way max bank aliasing (free, m136)
// ---------------------------------------------------------------------------
__device__ inline int lds_idx(int row, int chunk) {
  return row * 32 + ((chunk ^ ((row >> 1) & 3)) << 3);   // u16 units
}

// ---------------------------------------------------------------------------
// Fallback bf16 MFMA GEMM (B fp32, converted at stage) -- round-6 verified.
// ---------------------------------------------------------------------------
__global__ __launch_bounds__(256) void gemm_bf16_mfma(
    const u16* __restrict__ A, const float* __restrict__ B,
    const float* __restrict__ bias, float* __restrict__ C, int M, int N, int K)
{
  __shared__ u16 As[128 * 32];
  __shared__ u16 Bs[128 * 32];
  const int tid = threadIdx.x;
  const int lane = tid & 63;
  const int wv = tid >> 6;
  const int wr = wv >> 1, wc = wv & 1;

  const int nmt = M >> 7;
  const int chunk_sz = (int)gridDim.x >> 3;
  const int bid = (int)blockIdx.x;
  const int wg = (bid & 7) * chunk_sz + (bid >> 3);
  const int bm = (wg % nmt) * 128;
  const int bn = (wg / nmt) * 128;

  const int srow = tid >> 1;
  const int c0 = (tid & 1) << 1;

  const u16*  Ap = A + (size_t)(bm + srow) * K + (c0 << 3);
  const float* Bp = B + (size_t)(bn + srow) * K + (c0 << 3);

  f32x4 acc[4][4];
#pragma unroll
  for (int i = 0; i < 4; ++i)
#pragma unroll
    for (int j = 0; j < 4; ++j) acc[i][j] = (f32x4){0.f, 0.f, 0.f, 0.f};

  f32x4 a0 = *(const f32x4*)(Ap);
  f32x4 a1 = *(const f32x4*)(Ap + 8);
  float4 q0 = *(const float4*)(Bp);
  float4 q1 = *(const float4*)(Bp + 4);
  float4 q2 = *(const float4*)(Bp + 8);
  float4 q3 = *(const float4*)(Bp + 12);

  for (int k0 = 0; k0 < K; k0 += 32) {
    *(f32x4*)(&As[lds_idx(srow, c0)]) = a0;
    *(f32x4*)(&As[lds_idx(srow, c0 + 1)]) = a1;
    uint4 w0, w1;
    w0.x = pack2bf(q0.x, q0.y); w0.y = pack2bf(q0.z, q0.w);
    w0.z = pack2bf(q1.x, q1.y); w0.w = pack2bf(q1.z, q1.w);
    w1.x = pack2bf(q2.x, q2.y); w1.y = pack2bf(q2.z, q2.w);
    w1.z = pack2bf(q3.x, q3.y); w1.w = pack2bf(q3.z, q3.w);
    *(uint4*)(&Bs[lds_idx(srow, c0)]) = w0;
    *(uint4*)(&Bs[lds_idx(srow, c0 + 1)]) = w1;
    __syncthreads();

    if (k0 + 32 < K) {
      a0 = *(const f32x4*)(Ap + k0 + 32);
      a1 = *(const f32x4*)(Ap + k0 + 40);
      q0 = *(const float4*)(Bp + k0 + 32);
      q1 = *(const float4*)(Bp + k0 + 36);
      q2 = *(const float4*)(Bp + k0 + 40);
      q3 = *(const float4*)(Bp + k0 + 44);
    }

    bf16x8 af[4], bfr[4];
#pragma unroll
    for (int mi = 0; mi < 4; ++mi)
      af[mi] = *(const bf16x8*)(&As[lds_idx(wr * 64 + mi * 16 + (lane & 15), lane >> 4)]);
#pragma unroll
    for (int ni = 0; ni < 4; ++ni)
      bfr[ni] = *(const bf16x8*)(&Bs[lds_idx(wc * 64 + ni * 16 + (lane & 15), lane >> 4)]);
#pragma unroll
    for (int mi = 0; mi < 4; ++mi)
#pragma unroll
      for (int ni = 0; ni < 4; ++ni)
        acc[mi][ni] = __builtin_amdgcn_mfma_f32_16x16x32_bf16(af[mi], bfr[ni], acc[mi][ni], 0, 0, 0);
    __syncthreads();
  }

  const int r0 = bm + wr * 64 + ((lane >> 4) << 2);
  const int cc0 = bn + wc * 64 + (lane & 15);
#pragma unroll
  for (int mi = 0; mi < 4; ++mi)
#pragma unroll
    for (int ni = 0; ni < 4; ++ni) {
      const int col = cc0 + ni * 16;
      const float bv = bias[col];
#pragma unroll
      for (int r = 0; r < 4; ++r)
        C[(size_t)(r0 + mi * 16 + r) * N + col] = acc[mi][ni][r] + bv;
    }
}

// ---------------------------------------------------------------------------
// m97-structure GEMM: both operands bf16, global_load_lds width=16,
// pre-swizzled global source + lds_idx reads (linear LDS dest).
// ---------------------------------------------------------------------------
__global__ __launch_bounds__(256) void gemm_bf16x2_mfma(
    const u16* __restrict__ A, const u16* __restrict__ B,
    const float* __restrict__ bias, float* __restrict__ C, int M, int N, int K)
{
  __shared__ u16 As[128 * 32];
  __shared__ u16 Bs[128 * 32];
  const int tid = threadIdx.x;
  const int lane = tid & 63;
  const int wv = tid >> 6;
  const int wr = wv >> 1, wc = wv & 1;

  const int nmt = M >> 7;
  const int chunk_sz = (int)gridDim.x >> 3;
  const int bid = (int)blockIdx.x;
  const int wg = (bid & 7) * chunk_sz + (bid >> 3);
  const int bm = (wg % nmt) * 128;
  const int bn = (wg / nmt) * 128;

  // staging: 16 segments of 1KB (A segs 0-7, B segs 8-15); wave wv owns 4.
  const int rseg = lane >> 2;     // row within 16-row segment
  const int cch = lane & 3;       // raw 16B chunk
  const u16* gsrc[4];
  u16* ldst[4];
#pragma unroll
  for (int i = 0; i < 4; ++i) {
    const int s = wv * 4 + i;
    const int row = (s & 7) * 16 + rseg;          // tile row 0..127
    const int ch = cch ^ ((row >> 1) & 3);        // pre-swizzle (inverse of lds_idx)
    if (s < 8) {
      gsrc[i] = A + (size_t)(bm + row) * K + ch * 8;
      ldst[i] = &As[s * 512];
    } else {
      gsrc[i] = B + (size_t)(bn + row) * K + ch * 8;
      ldst[i] = &Bs[(s - 8) * 512];
    }
  }

  f32x4 acc[4][4];
#pragma unroll
  for (int i = 0; i < 4; ++i)
#pragma unroll
    for (int j = 0; j < 4; ++j) acc[i][j] = (f32x4){0.f, 0.f, 0.f, 0.f};

  for (int k0 = 0; k0 < K; k0 += 32) {
#pragma unroll
    for (int i = 0; i < 4; ++i)
      gload_lds16(gsrc[i] + k0, ldst[i]);
    __syncthreads();                 // drains vmcnt before barrier

    bf16x8 af[4], bfr[4];
#pragma unroll
    for (int mi = 0; mi < 4; ++mi)
      af[mi] = *(const bf16x8*)(&As[lds_idx(wr * 64 + mi * 16 + (lane & 15), lane >> 4)]);
#pragma unroll
    for (int ni = 0; ni < 4; ++ni)
      bfr[ni] = *(const bf16x8*)(&Bs[lds_idx(wc * 64 + ni * 16 + (lane & 15), lane >> 4)]);
#pragma unroll
    for (int mi = 0; mi < 4; ++mi)
#pragma unroll
      for (int ni = 0; ni < 4; ++ni)
        acc[mi][ni] = __builtin_amdgcn_mfma_f32_16x16x32_bf16(af[mi], bfr[ni], acc[mi][ni], 0, 0, 0);
    __syncthreads();
  }

  const int r0 = bm + wr * 64 + ((lane >> 4) << 2);
  const int cc0 = bn + wc * 64 + (lane & 15);
#pragma unroll
  for (int mi = 0; mi < 4; ++mi)
#pragma unroll
    for (int ni = 0; ni < 4; ++ni) {
      const int col = cc0 + ni * 16;
      const float bv = bias[col];
#pragma unroll
      for (int r = 0; r < 4; ++r)
        C[(size_t)(r0 + mi * 16 + r) * N + col] = acc[mi][ni][r] + bv;
    }
}

// ---------------------------------------------------------------------------
// gen_w fp32 -> bf16 (same layout), 8 elems/thread
// ---------------------------------------------------------------------------
__global__ __launch_bounds__(256) void cvt_f32_bf16_kernel(
    const float* __restrict__ src, u16* __restrict__ dst, int n8)
{
  const int i = blockIdx.x * 256 + threadIdx.x;
  if (i >= n8) return;
  const float4 s0 = ((const float4*)src)[2 * i];
  const float4 s1 = ((const float4*)src)[2 * i + 1];
  uint4 w;
  w.x = pack2bf(s0.x, s0.y); w.y = pack2bf(s0.z, s0.w);
  w.z = pack2bf(s1.x, s1.y); w.w = pack2bf(s1.z, s1.w);
  ((uint4*)dst)[i] = w;
}

// ---------------------------------------------------------------------------
// Attention / misc small kernels (unchanged)
// ---------------------------------------------------------------------------
__global__ __launch_bounds__(64) void scores_kernel(
    const float* __restrict__ enc, const float* __restrict__ ht,
    float* __restrict__ sc)
{
  const int sb = blockIdx.x;
  const int b = sb % BATCH;
  const int lane = threadIdx.x;
  const float* e = enc + (size_t)sb * DH;
  const float* h = ht + (size_t)b * DH;
  float sum = 0.f;
  for (int k = lane * 4; k < DH; k += 64 * 4) {
    float4 ev = *reinterpret_cast<const float4*>(e + k);
    float4 hv = *reinterpret_cast<const float4*>(h + k);
    sum += ev.x * hv.x + ev.y * hv.y + ev.z * hv.z + ev.w * hv.w;
  }
#pragma unroll
  for (int off = 32; off; off >>= 1) sum += __shfl_down(sum, off);
  if (lane == 0) sc[sb] = sum;
}

__global__ __launch_bounds__(64) void logsoftmax_kernel(
    const float* __restrict__ sc, float* __restrict__ a)
{
  const int s = threadIdx.x;
  if (s >= SRC) return;
  const float* r = sc + (size_t)s * BATCH;
  float m = -INFINITY;
  for (int b = 0; b < BATCH; ++b) m = fmaxf(m, r[b]);
  float sum = 0.f;
  for (int b = 0; b < BATCH; ++b) sum += expf(r[b] - m);
  const float lse = m + logf(sum);
  float* o = a + (size_t)s * BATCH;
  for (int b = 0; b < BATCH; ++b) o[b] = r[b] - lse;
}

__global__ __launch_bounds__(256) void ctxsum_kernel(
    const float* __restrict__ a, const float* __restrict__ enc,
    const float* __restrict__ hidden, float* __restrict__ cat)
{
  const int b = blockIdx.x;
  const int d = blockIdx.y * 256 + threadIdx.x;
  float sum = 0.f;
  for (int s = 0; s < SRC; ++s)
    sum = fmaf(a[s * BATCH + b], enc[(size_t)(s * BATCH + b) * DH + d], sum);
  cat[(size_t)b * (2 * DH) + d] = sum;
  cat[(size_t)b * (2 * DH) + DH + d] = hidden[(size_t)b * DH + d];
}

__global__ __launch_bounds__(256) void gather_kernel(
    const int* __restrict__ targ, const float* __restrict__ emb,
    float* __restrict__ embedded)
{
  const int tb = blockIdx.x;
  const int tok = targ[tb];
  const float* src = emb + (size_t)tok * EMB;
  float* dst = embedded + (size_t)tb * EMB;
  for (int j = threadIdx.x; j < EMB; j += blockDim.x) dst[j] = src[j];
}

// ---------------------------------------------------------------------------
// Pack w_hh -> bf16 MFMA B-frag layout (round 6, verified)
// ---------------------------------------------------------------------------
__global__ __launch_bounds__(64) void pack_whh_kernel(
    const float* __restrict__ w_hh, u16* __restrict__ wpack)
{
  const int bid = blockIdx.x;           // 8192
  const int k0 = bid & 31;
  const int g = (bid >> 5) & 3;
  const int jt = bid >> 7;
  const int l = threadIdx.x;
  const int row = g * 1024 + jt * 16 + (l & 15);
  const int col = k0 * 32 + (l >> 4) * 8;
  const float* src = w_hh + (size_t)row * DH + col;
  u16* dst = wpack + ((size_t)bid * 64 + l) * 8;
  uint4 w;
  float4 s0 = *(const float4*)(src);
  float4 s1 = *(const float4*)(src + 4);
  w.x = pack2bf(s0.x, s0.y); w.y = pack2bf(s0.z, s0.w);
  w.z = pack2bf(s1.x, s1.y); w.w = pack2bf(s1.z, s1.w);
  *(uint4*)dst = w;
}

__global__ void init_bar_kernel(unsigned* bar) {
  if (threadIdx.x < 8) bar[threadIdx.x] = 0u;
}

// ---------------------------------------------------------------------------
// Persistent LSTM v2.  64 blocks x 768 thr (12 waves = 4 gates x 3 m-tiles).
// Changes vs v1: (a) RELAXED spin polling + single acquire fence after the
// loop (v1's per-poll ACQUIRE emitted buffer_inv per iteration -> L2 thrash,
// 12.7us/step); (b) xg for step t+1 prefetched into registers before the
// device barrier (HBM latency hidden under act+barrier).
// ---------------------------------------------------------------------------
__global__ __launch_bounds__(768, 1) void lstm_persistent(
    const u16* __restrict__ wpack,      // [64][4][32][64][8]
    const float* __restrict__ xg,       // [T*48, 4096], ctx+biases folded
    u16* __restrict__ hbuf0, u16* __restrict__ hbuf1,  // packed [3][32][64][8]
    u16* __restrict__ hs,               // [T][48][1024] row-major
    unsigned* bar)
{
  __shared__ float gate_s[4][48][16];
  const int jt = (int)blockIdx.x;       // 0..63
  const int tid = (int)threadIdx.x;
  const int l = tid & 63;
  const int wv = tid >> 6;              // 0..11
  const int g = wv & 3;
  const int mi = wv >> 2;               // 0..2
  const int ab = tid >> 4;              // act: batch 0..47
  const int aj = tid & 15;              // act: j within tile
  const int ajj = jt * 16 + aj;
  float c_reg = 0.f;

  const u16* wp = wpack + (((size_t)(jt * 4 + g) * 32) * 64 + l) * 8;
  // packed-h write offset for act thread (ab, ajj)
  const int w_mi = ab >> 4, w_r = ab & 15;
  const int w_k0 = ajj >> 5, w_sub = (ajj & 31) >> 3, w_e = ajj & 7;
  const size_t w_off =
      ((size_t)((w_mi * 32 + w_k0) * 64) + w_sub * 16 + w_r) * 8 + w_e;

  // prefetch xg for t=0
  size_t xb = (size_t)ab * GDIM + ajj;
  float p_i = xg[xb + 0 * DH];
  float p_f = xg[xb + 1 * DH];
  float p_g = xg[xb + 2 * DH];
  float p_o = xg[xb + 3 * DH];

  for (int t = 0; t < T_LEN; ++t) {
    if (t > 0) {
      const u16* hp = (t & 1) ? hbuf0 : hbuf1;   // h(t-1) = buf[(t-1)&1]
      const u16* hpm = hp + ((size_t)(mi * 32) * 64 + l) * 8;
      f32x4 acc = {0.f, 0.f, 0.f, 0.f};
#pragma unroll 8
      for (int k0 = 0; k0 < 32; ++k0) {
        bf16x8 bfrag = *(const bf16x8*)(wp + (size_t)k0 * 512);
        bf16x8 afrag = *(const bf16x8*)(hpm + (size_t)k0 * 512);
        acc = __builtin_amdgcn_mfma_f32_16x16x32_bf16(afrag, bfrag, acc, 0, 0, 0);
      }
      const int rr = (l >> 4) << 2;
      const int cc = l & 15;
#pragma unroll
      for (int r = 0; r < 4; ++r)
        gate_s[g][mi * 16 + rr + r][cc] = acc[r];
    }
    __syncthreads();

    // act: thread == one (b, j); xg values already in registers
    {
      float gi = p_i, gf = p_f, gg = p_g, go = p_o;
      if (t > 0) {
        gi += gate_s[0][ab][aj];
        gf += gate_s[1][ab][aj];
        gg += gate_s[2][ab][aj];
        go += gate_s[3][ab][aj];
      }
      const float si = 1.f / (1.f + expf(-gi));
      const float sf = 1.f / (1.f + expf(-gf));
      const float so = 1.f / (1.f + expf(-go));
      const float tg = tanhf(gg);
      c_reg = sf * c_reg + si * tg;
      const float h = so * tanhf(c_reg);
      const u16 hb = f2bf(h);
      hs[(size_t)t * BATCH * DH + (size_t)ab * DH + ajj] = hb;
      u16* hw = (t & 1) ? hbuf1 : hbuf0;         // h(t) = buf[t&1]
      hw[w_off] = hb;
    }

    // prefetch xg for t+1 (hides HBM latency under act+barrier)
    if (t + 1 < T_LEN) {
      xb = ((size_t)(t + 1) * BATCH + ab) * GDIM + ajj;
      p_i = xg[xb + 0 * DH];
      p_f = xg[xb + 1 * DH];
      p_g = xg[xb + 2 * DH];
      p_o = xg[xb + 3 * DH];
    }

    // device-wide barrier: relaxed spin + one release/acquire fence pair
    __syncthreads();                              // block's stores issued
    if (tid == 0) {
      __threadfence();                            // release: wb L2 once
      __hip_atomic_fetch_add(bar, 1u, __ATOMIC_RELAXED, __HIP_MEMORY_SCOPE_AGENT);
      const unsigned target = (unsigned)NBLK_L * (unsigned)(t + 1);
      while (__hip_atomic_load(bar, __ATOMIC_RELAXED, __HIP_MEMORY_SCOPE_AGENT) < target)
        __builtin_amdgcn_s_sleep(1);
      __builtin_amdgcn_fence(__ATOMIC_ACQUIRE, "agent");  // inv once
    }
    __syncthreads();
  }
}

// ---------------------------------------------------------------------------
extern "C" void kernel_launch(void* const* d_in, const int* in_sizes, int n_in,
                              void* d_out, int out_size, void* d_ws, size_t ws_size,
                              hipStream_t stream) {
  const int*   targ     = (const int*)d_in[0];
  const float* enc      = (const float*)d_in[1];
  const float* emb      = (const float*)d_in[2];
  const float* attin_w  = (const float*)d_in[3];
  const float* attin_b  = (const float*)d_in[4];
  const float* attout_w = (const float*)d_in[5];
  const float* attout_b = (const float*)d_in[6];
  const float* gen_w    = (const float*)d_in[7];
  const float* gen_b    = (const float*)d_in[8];
  const float* hidden   = (const float*)d_in[9];
  const float* w_ih     = (const float*)d_in[10];
  const float* w_hh     = (const float*)d_in[11];
  const float* b_ih     = (const float*)d_in[12];
  const float* b_hh     = (const float*)d_in[13];
  float* out = (float*)d_out;

  char* wsp = (char*)d_ws;
  auto alloc = [&](size_t bytes) {
    char* p = wsp;
    wsp += (bytes + 255) & ~(size_t)255;
    return p;
  };
  float* ht       = (float*)alloc((size_t)BATCH * DH * 4);
  float* sc       = (float*)alloc((size_t)SRC * BATCH * 4);
  float* attn     = (float*)alloc((size_t)SRC * BATCH * 4);
  float* cat      = (float*)alloc((size_t)BATCH * 2 * DH * 4);
  float* ctx      = (float*)alloc((size_t)BATCH * DH * 4);
  float* ctxpart  = (float*)alloc((size_t)BATCH * GDIM * 4);
  float* embedded = (float*)alloc((size_t)T_LEN * BATCH * EMB * 4);
  float* xg       = (float*)alloc((size_t)T_LEN * BATCH * GDIM * 4);
  u16*   wpack    = (u16*)alloc((size_t)GDIM * DH * 2);
  u16*   hbuf0    = (u16*)alloc((size_t)3 * 32 * 64 * 8 * 2);
  u16*   hbuf1    = (u16*)alloc((size_t)3 * 32 * 64 * 8 * 2);
  u16*   hs_bf16  = (u16*)alloc((size_t)T_LEN * BATCH * DH * 2);
  unsigned* bar   = (unsigned*)alloc(256);
  u16*   genw_bf16 = (u16*)alloc((size_t)VOC * DH * 2);   // LAST (guarded)
  const bool bigB = (size_t)(wsp - (char*)d_ws) <= ws_size;

  // 0. one-off weight reshapes
  pack_whh_kernel<<<64 * 4 * 32, 64, 0, stream>>>(w_hh, wpack);
  if (bigB)
    cvt_f32_bf16_kernel<<<(VOC * DH / 8 + 255) / 256, 256, 0, stream>>>(
        gen_w, genw_bf16, VOC * DH / 8);

  // 1. ht = hidden @ attin_w^T + attin_b
  gemm_abt<0><<<dim3(1, DH / BN), 256, 0, stream>>>(
      hidden, DH, attin_w, DH, attin_b, nullptr, nullptr, 1, ht, DH, BATCH, DH, DH);

  // 2-4. scores, log_softmax(axis=batch), context sum
  scores_kernel<<<SRC * BATCH, 64, 0, stream>>>(enc, ht, sc);
  logsoftmax_kernel<<<1, 64, 0, stream>>>(sc, attn);
  ctxsum_kernel<<<dim3(BATCH, DH / 256), 256, 0, stream>>>(attn, enc, hidden, cat);

  // 5. context = tanh(cat @ attout_w^T + attout_b)
  gemm_abt<1><<<dim3(1, DH / BN), 256, 0, stream>>>(
      cat, 2 * DH, attout_w, 2 * DH, attout_b, nullptr, nullptr, 1, ctx, DH, BATCH, DH, 2 * DH);

  // 6. ctxpart = context @ w_ih[:, :1024]^T + b_ih + b_hh
  gemm_abt<0><<<dim3(1, GDIM / BN), 256, 0, stream>>>(
      ctx, DH, w_ih, XDIM, b_ih, b_hh, nullptr, 1, ctxpart, GDIM, BATCH, GDIM, DH);

  // 7. embedded = emb[targ]
  gather_kernel<<<T_LEN * BATCH, 256, 0, stream>>>(targ, emb, embedded);

  // 8. xg = embedded @ w_ih[:, 1024:]^T  (+ ctxpart folded per row b=gr%48)
  gemm_abt<0><<<dim3(T_LEN * BATCH / BM, GDIM / BN), 256, 0, stream>>>(
      embedded, EMB, w_ih + DH, XDIM, nullptr, nullptr, ctxpart, BATCH,
      xg, GDIM, T_LEN * BATCH, GDIM, EMB);

  // 9. persistent LSTM (single launch, device-wide barrier per step)
  init_bar_kernel<<<1, 64, 0, stream>>>(bar);
  lstm_persistent<<<NBLK_L, 768, 0, stream>>>(wpack, xg, hbuf0, hbuf1, hs_bf16, bar);

  // 10. out = hs @ gen_w^T + gen_b
  if (bigB)
    gemm_bf16x2_mfma<<<(T_LEN * BATCH / 128) * (VOC / 128), 256, 0, stream>>>(
        hs_bf16, genw_bf16, gen_b, out, T_LEN * BATCH, VOC, DH);
  else
    gemm_bf16_mfma<<<(T_LEN * BATCH / 128) * (VOC / 128), 256, 0, stream>>>(
        hs_bf16, gen_w, gen_b, out, T_LEN * BATCH, VOC, DH);
}